// Round 2
// baseline (20688.144 us; speedup 1.0000x reference)
//
#include <hip/hip_runtime.h>
#include <hip/hip_fp16.h>

#define NLAYERS 4

// ---------------- zero fill (float4 granular) ----------------
__global__ void zero_kernel(float4* __restrict__ p, long n4) {
    long i = (long)blockIdx.x * 256 + threadIdx.x;
    long stride = (long)gridDim.x * 256;
    float4 z = make_float4(0.f, 0.f, 0.f, 0.f);
    for (; i < n4; i += stride) p[i] = z;
}

// ---------------- encoder: out = relu(x @ W + b), x [n,kin], W [kin,32] ----------------
__global__ void enc_kernel(const float* __restrict__ x, const float* __restrict__ W,
                           const float* __restrict__ b, float* __restrict__ out,
                           int n, int kin) {
    __shared__ float sW[53 * 32];
    __shared__ float sb[32];
    __shared__ float sx[8][56];
    int tid = threadIdx.x;
    for (int i = tid; i < kin * 32; i += 256) sW[i] = W[i];
    if (tid < 32) sb[tid] = b[tid];
    int local = tid >> 5, f = tid & 31;
    int node = blockIdx.x * 8 + local;
    __syncthreads();
    if (node < n) {
        for (int k = f; k < kin; k += 32) sx[local][k] = x[(size_t)node * kin + k];
    }
    __syncthreads();
    if (node >= n) return;
    float acc = sb[f];
    for (int k = 0; k < kin; k++) acc += sx[local][k] * sW[k * 32 + f];
    out[(size_t)node * 32 + f] = fmaxf(acc, 0.0f);
}

// ---------------- projection for addr: h(half) = x@W+b; asrc0/adst1 per head ----------------
__global__ void proj_addr_kernel(const float* __restrict__ x,
                                 const float* __restrict__ W, const float* __restrict__ b,
                                 const float* __restrict__ a0, const float* __restrict__ a1,
                                 __half* __restrict__ h, float* __restrict__ o0,
                                 float* __restrict__ o1, int n) {
    __shared__ float sW[1024];
    __shared__ float sv[3][32];
    __shared__ float sx[8][33];
    __shared__ float sh[8][33];
    int tid = threadIdx.x;
    for (int i = tid; i < 1024; i += 256) sW[i] = W[i];
    if (tid < 32) { sv[0][tid] = b[tid]; sv[1][tid] = a0[tid]; sv[2][tid] = a1[tid]; }
    int local = tid >> 5, f = tid & 31;
    int node = blockIdx.x * 8 + local;
    __syncthreads();
    if (node < n) sx[local][f] = x[(size_t)node * 32 + f];
    __syncthreads();
    if (node < n) {
        float acc = sv[0][f];
        #pragma unroll
        for (int k = 0; k < 32; k++) acc += sx[local][k] * sW[k * 32 + f];
        h[(size_t)node * 32 + f] = __float2half(acc);
        sh[local][f] = acc;
    }
    __syncthreads();
    if (node < n && f < 8) {
        int vec = f >> 2, head = f & 3;
        const float* av = sv[1 + vec];
        float dsum = 0.f;
        #pragma unroll
        for (int dd = 0; dd < 8; dd++) dsum += sh[local][head * 8 + dd] * av[head * 8 + dd];
        (vec == 0 ? o0 : o1)[(size_t)node * 4 + head] = dsum;
    }
}

// ---------------- projection for tx: h(half) + 4 attention vectors ----------------
__global__ void proj_tx_kernel(const float* __restrict__ x,
                               const float* __restrict__ W, const float* __restrict__ b,
                               const float* __restrict__ a0, const float* __restrict__ a1,
                               const float* __restrict__ a2, const float* __restrict__ a3,
                               __half* __restrict__ h,
                               float* __restrict__ o0, float* __restrict__ o1,
                               float* __restrict__ o2, float* __restrict__ o3, int n) {
    __shared__ float sW[1024];
    __shared__ float sv[5][32];
    __shared__ float sx[8][33];
    __shared__ float sh[8][33];
    int tid = threadIdx.x;
    for (int i = tid; i < 1024; i += 256) sW[i] = W[i];
    if (tid < 32) {
        sv[0][tid] = b[tid]; sv[1][tid] = a0[tid]; sv[2][tid] = a1[tid];
        sv[3][tid] = a2[tid]; sv[4][tid] = a3[tid];
    }
    int local = tid >> 5, f = tid & 31;
    int node = blockIdx.x * 8 + local;
    __syncthreads();
    if (node < n) sx[local][f] = x[(size_t)node * 32 + f];
    __syncthreads();
    if (node < n) {
        float acc = sv[0][f];
        #pragma unroll
        for (int k = 0; k < 32; k++) acc += sx[local][k] * sW[k * 32 + f];
        h[(size_t)node * 32 + f] = __float2half(acc);
        sh[local][f] = acc;
    }
    __syncthreads();
    if (node < n && f < 16) {
        int vec = f >> 2, head = f & 3;
        const float* av = sv[1 + vec];
        float dsum = 0.f;
        #pragma unroll
        for (int dd = 0; dd < 8; dd++) dsum += sh[local][head * 8 + dd] * av[head * 8 + dd];
        float* op = vec == 0 ? o0 : vec == 1 ? o1 : vec == 2 ? o2 : o3;
        op[(size_t)node * 4 + head] = dsum;
    }
}

__device__ __forceinline__ float leaky02(float v) { return v > 0.f ? v : 0.2f * v; }

// ---------------- edge pass 1: den[di] += exp(leaky(asrc[si]+adst[di])) ----------------
__global__ void edge_den_kernel(const int* __restrict__ si, const int* __restrict__ di,
                                const float* __restrict__ asrc, const float* __restrict__ adst,
                                float* __restrict__ den, int E) {
    int e = blockIdx.x * 256 + threadIdx.x;
    if (e >= E) return;
    int s = si[e], d = di[e];
    float4 a = *(const float4*)(asrc + (size_t)s * 4);
    float4 bb = *(const float4*)(adst + (size_t)d * 4);
    float e0 = __expf(leaky02(a.x + bb.x));
    float e1 = __expf(leaky02(a.y + bb.y));
    float e2 = __expf(leaky02(a.z + bb.z));
    float e3 = __expf(leaky02(a.w + bb.w));
    float* dp = den + (size_t)d * 4;
    unsafeAtomicAdd(dp + 0, e0);
    unsafeAtomicAdd(dp + 1, e1);
    unsafeAtomicAdd(dp + 2, e2);
    unsafeAtomicAdd(dp + 3, e3);
}

// ---------------- edge pass 2: agg[di] += h_s[si] * exp(...)/(den[di]+eps) ----------------
__global__ void edge_agg_kernel(const int* __restrict__ si, const int* __restrict__ di,
                                const __half* __restrict__ hs,
                                const float* __restrict__ asrc, const float* __restrict__ adst,
                                const float* __restrict__ den, float* __restrict__ agg, int E) {
    int e = blockIdx.x * 256 + threadIdx.x;
    if (e >= E) return;
    int s = si[e], d = di[e];
    float4 a = *(const float4*)(asrc + (size_t)s * 4);
    float4 bb = *(const float4*)(adst + (size_t)d * 4);
    float4 dn = *(const float4*)(den + (size_t)d * 4);
    float w[4];
    w[0] = __expf(leaky02(a.x + bb.x)) / (dn.x + 1e-16f);
    w[1] = __expf(leaky02(a.y + bb.y)) / (dn.y + 1e-16f);
    w[2] = __expf(leaky02(a.z + bb.z)) / (dn.z + 1e-16f);
    w[3] = __expf(leaky02(a.w + bb.w)) / (dn.w + 1e-16f);
    const float4* hp = (const float4*)(hs + (size_t)s * 32);  // 4 x (8 halfs)
    float* ag = agg + (size_t)d * 32;
    #pragma unroll
    for (int h = 0; h < 4; h++) {
        float4 raw = hp[h];
        const __half2* hh = (const __half2*)&raw;
        float wh = w[h];
        #pragma unroll
        for (int j = 0; j < 4; j++) {
            float2 v = __half22float2(hh[j]);
            unsafeAtomicAdd(ag + h * 8 + 2 * j + 0, v.x * wh);
            unsafeAtomicAdd(ag + h * 8 + 2 * j + 1, v.y * wh);
        }
    }
}

// ---------------- semantic score: score += sum_n q . tanh(relu(agg[n]) @ kw + kb) ----------------
__global__ void score_kernel(const float* __restrict__ agg, const float* __restrict__ kw,
                             const float* __restrict__ kb, const float* __restrict__ q,
                             float* __restrict__ score, int n) {
    __shared__ float sW[1024];
    __shared__ float sb[32];
    __shared__ float sq[32];
    int tid = threadIdx.x;
    for (int i = tid; i < 1024; i += 256) sW[i] = kw[i];
    if (tid < 32) { sb[tid] = kb[tid]; sq[tid] = q[tid]; }
    __syncthreads();
    int node = blockIdx.x * 256 + tid;
    float acc = 0.f;
    if (node < n) {
        float xr[32];
        const float4* p = (const float4*)(agg + (size_t)node * 32);
        #pragma unroll
        for (int i = 0; i < 8; i++) {
            float4 v = p[i];
            xr[4 * i + 0] = fmaxf(v.x, 0.f);
            xr[4 * i + 1] = fmaxf(v.y, 0.f);
            xr[4 * i + 2] = fmaxf(v.z, 0.f);
            xr[4 * i + 3] = fmaxf(v.w, 0.f);
        }
        for (int f = 0; f < 32; f++) {
            float y = sb[f];
            #pragma unroll
            for (int k = 0; k < 32; k++) y += xr[k] * sW[k * 32 + f];
            acc += sq[f] * tanhf(y);
        }
    }
    #pragma unroll
    for (int off = 32; off > 0; off >>= 1) acc += __shfl_down(acc, off, 64);
    if ((tid & 63) == 0) unsafeAtomicAdd(score, acc);
}

// ---------------- combine addr: xa = LN(relu(agg) + xa) ----------------
__global__ void combine_addr_kernel(const float* __restrict__ agg, float* __restrict__ xa,
                                    const float* __restrict__ g, const float* __restrict__ bt, int n) {
    int node = blockIdx.x * 256 + threadIdx.x;
    if (node >= n) return;
    float v[32];
    const float4* ap = (const float4*)(agg + (size_t)node * 32);
    float4* xp = (float4*)(xa + (size_t)node * 32);
    #pragma unroll
    for (int i = 0; i < 8; i++) {
        float4 a = ap[i]; float4 x = xp[i];
        v[4 * i + 0] = fmaxf(a.x, 0.f) + x.x;
        v[4 * i + 1] = fmaxf(a.y, 0.f) + x.y;
        v[4 * i + 2] = fmaxf(a.z, 0.f) + x.z;
        v[4 * i + 3] = fmaxf(a.w, 0.f) + x.w;
    }
    float m = 0.f;
    #pragma unroll
    for (int f = 0; f < 32; f++) m += v[f];
    m *= (1.f / 32.f);
    float var = 0.f;
    #pragma unroll
    for (int f = 0; f < 32; f++) { float dd = v[f] - m; var += dd * dd; }
    var *= (1.f / 32.f);
    float inv = 1.f / sqrtf(var + 1e-5f);
    #pragma unroll
    for (int i = 0; i < 8; i++) {
        float4 o;
        o.x = (v[4 * i + 0] - m) * inv * g[4 * i + 0] + bt[4 * i + 0];
        o.y = (v[4 * i + 1] - m) * inv * g[4 * i + 1] + bt[4 * i + 1];
        o.z = (v[4 * i + 2] - m) * inv * g[4 * i + 2] + bt[4 * i + 2];
        o.w = (v[4 * i + 3] - m) * inv * g[4 * i + 3] + bt[4 * i + 3];
        xp[i] = o;
    }
}

// ---------------- combine tx: xt = LN(relu(w0*relu(agg0)+w2*relu(agg2)) + xt) ----------------
__global__ void combine_tx_kernel(const float* __restrict__ agg0, const float* __restrict__ agg2,
                                  float* __restrict__ xt, const float* __restrict__ scores,
                                  const float* __restrict__ g, const float* __restrict__ bt,
                                  int n, float invN) {
    int node = blockIdx.x * 256 + threadIdx.x;
    if (node >= n) return;
    float s0 = scores[0] * invN, s2 = scores[1] * invN;
    float mx = fmaxf(s0, s2);
    float e0 = __expf(s0 - mx), e2 = __expf(s2 - mx);
    float inv_s = 1.f / (e0 + e2);
    float w0 = e0 * inv_s, w2 = e2 * inv_s;
    float v[32];
    const float4* a0p = (const float4*)(agg0 + (size_t)node * 32);
    const float4* a2p = (const float4*)(agg2 + (size_t)node * 32);
    float4* xp = (float4*)(xt + (size_t)node * 32);
    #pragma unroll
    for (int i = 0; i < 8; i++) {
        float4 a = a0p[i]; float4 c = a2p[i]; float4 x = xp[i];
        v[4 * i + 0] = fmaxf(w0 * fmaxf(a.x, 0.f) + w2 * fmaxf(c.x, 0.f), 0.f) + x.x;
        v[4 * i + 1] = fmaxf(w0 * fmaxf(a.y, 0.f) + w2 * fmaxf(c.y, 0.f), 0.f) + x.y;
        v[4 * i + 2] = fmaxf(w0 * fmaxf(a.z, 0.f) + w2 * fmaxf(c.z, 0.f), 0.f) + x.z;
        v[4 * i + 3] = fmaxf(w0 * fmaxf(a.w, 0.f) + w2 * fmaxf(c.w, 0.f), 0.f) + x.w;
    }
    float m = 0.f;
    #pragma unroll
    for (int f = 0; f < 32; f++) m += v[f];
    m *= (1.f / 32.f);
    float var = 0.f;
    #pragma unroll
    for (int f = 0; f < 32; f++) { float dd = v[f] - m; var += dd * dd; }
    var *= (1.f / 32.f);
    float inv = 1.f / sqrtf(var + 1e-5f);
    #pragma unroll
    for (int i = 0; i < 8; i++) {
        float4 o;
        o.x = (v[4 * i + 0] - m) * inv * g[4 * i + 0] + bt[4 * i + 0];
        o.y = (v[4 * i + 1] - m) * inv * g[4 * i + 1] + bt[4 * i + 1];
        o.z = (v[4 * i + 2] - m) * inv * g[4 * i + 2] + bt[4 * i + 2];
        o.w = (v[4 * i + 3] - m) * inv * g[4 * i + 3] + bt[4 * i + 3];
        xp[i] = o;
    }
}

// ---------------- final: out = xa @ lin_w + lin_b ----------------
__global__ void final_kernel(const float* __restrict__ xa, const float* __restrict__ w,
                             const float* __restrict__ b, float* __restrict__ out, int n) {
    __shared__ float sw[64];
    __shared__ float sb2[2];
    if (threadIdx.x < 64) sw[threadIdx.x] = w[threadIdx.x];
    if (threadIdx.x < 2) sb2[threadIdx.x] = b[threadIdx.x];
    __syncthreads();
    int node = blockIdx.x * 256 + threadIdx.x;
    if (node >= n) return;
    float a0 = sb2[0], a1 = sb2[1];
    const float* xr = xa + (size_t)node * 32;
    #pragma unroll
    for (int k = 0; k < 32; k++) {
        float xv = xr[k];
        a0 += xv * sw[k * 2 + 0];
        a1 += xv * sw[k * 2 + 1];
    }
    out[(size_t)node * 2 + 0] = a0;
    out[(size_t)node * 2 + 1] = a1;
}

extern "C" void kernel_launch(void* const* d_in, const int* in_sizes, int n_in,
                              void* d_out, int out_size, void* d_ws, size_t ws_size,
                              hipStream_t stream) {
    const float* x_addr = (const float*)d_in[0];
    const float* x_tx   = (const float*)d_in[1];
    const int* ei_in    = (const int*)d_in[2];
    const int* ei_out   = (const int*)d_in[3];
    const int* ei_sp    = (const int*)d_in[4];
    const float* enc_w_addr = (const float*)d_in[5];
    const float* enc_b_addr = (const float*)d_in[6];
    const float* enc_w_tx   = (const float*)d_in[7];
    const float* enc_b_tx   = (const float*)d_in[8];
    const float* ln_ag = (const float*)d_in[9];
    const float* ln_ab = (const float*)d_in[10];
    const float* ln_tg = (const float*)d_in[11];
    const float* ln_tb = (const float*)d_in[12];
    const float* pw_a = (const float*)d_in[13];
    const float* pb_a = (const float*)d_in[14];
    const float* pw_t = (const float*)d_in[15];
    const float* pb_t = (const float*)d_in[16];
    const float* att_src = (const float*)d_in[17];
    const float* att_dst = (const float*)d_in[18];
    const float* klw = (const float*)d_in[19];
    const float* klb = (const float*)d_in[20];
    const float* qv  = (const float*)d_in[21];
    const float* lin_w = (const float*)d_in[22];
    const float* lin_b = (const float*)d_in[23];
    float* out = (float*)d_out;

    const int NA = in_sizes[0] / 53;
    const int NT = in_sizes[1] / 6;
    const int E_IN = in_sizes[2] / 2;
    const int E_OUT = in_sizes[3] / 2;
    const int E_SP = in_sizes[4] / 2;
    const int NMAX = NA > NT ? NA : NT;

    // ---- workspace layout (floats), each buffer 256B aligned ----
    size_t off = 0;
    float* base = (float*)d_ws;
    auto alloc = [&](size_t nfloats) {
        float* p = base + off;
        off += (nfloats + 63) & ~(size_t)63;
        return p;
    };
    float* xa      = alloc((size_t)NA * 32);
    float* xt      = alloc((size_t)NT * 32);
    float* agg_a   = alloc((size_t)NA * 32);   // first half of region doubles as h_a (fp16)
    float* agg_t0  = alloc((size_t)NT * 32);
    float* agg_t2  = alloc((size_t)NT * 32);
    float* h_t_f   = alloc((size_t)NT * 16);   // fp16 storage for h_t
    float* asrc0a  = alloc((size_t)NA * 4);
    float* adst1a  = alloc((size_t)NA * 4);
    float* asrc1t  = alloc((size_t)NT * 4);
    float* adst0t  = alloc((size_t)NT * 4);
    float* asrc2t  = alloc((size_t)NT * 4);
    float* adst2t  = alloc((size_t)NT * 4);
    float* den     = alloc((size_t)NMAX * 4);
    float* scores  = alloc(64);
    __half* h_a = (__half*)agg_a;   // alias: h_a dead before agg_a is zeroed (rel1)
    __half* h_t = (__half*)h_t_f;

    dim3 blk(256);
    int nbA8 = (NA + 7) / 8, nbT8 = (NT + 7) / 8;
    int nbA = (NA + 255) / 256, nbT = (NT + 255) / 256;

    auto zero = [&](float* p, size_t nfloats) {
        long n4 = (long)(nfloats / 4);
        int blocks = (int)((n4 + 255) / 256);
        if (blocks > 2048) blocks = 2048;
        if (blocks < 1) blocks = 1;
        zero_kernel<<<blocks, blk, 0, stream>>>((float4*)p, n4);
    };

    enc_kernel<<<nbA8, blk, 0, stream>>>(x_addr, enc_w_addr, enc_b_addr, xa, NA, 53);
    enc_kernel<<<nbT8, blk, 0, stream>>>(x_tx, enc_w_tx, enc_b_tx, xt, NT, 6);

    for (int l = 0; l < NLAYERS; l++) {
        const float* W_a = pw_a + l * 1024; const float* B_a = pb_a + l * 32;
        const float* W_t = pw_t + l * 1024; const float* B_t = pb_t + l * 32;
        const float* as0 = att_src + (l * 3 + 0) * 32;
        const float* as1 = att_src + (l * 3 + 1) * 32;
        const float* as2 = att_src + (l * 3 + 2) * 32;
        const float* ad0 = att_dst + (l * 3 + 0) * 32;
        const float* ad1 = att_dst + (l * 3 + 1) * 32;
        const float* ad2 = att_dst + (l * 3 + 2) * 32;

        proj_addr_kernel<<<nbA8, blk, 0, stream>>>(xa, W_a, B_a, as0, ad1, h_a, asrc0a, adst1a, NA);
        proj_tx_kernel<<<nbT8, blk, 0, stream>>>(xt, W_t, B_t, as1, ad0, as2, ad2,
                                                 h_t, asrc1t, adst0t, asrc2t, adst2t, NT);

        // rel0: addr -> tx over ei_input (reads h_a)
        zero(den, (size_t)NT * 4);
        zero(agg_t0, (size_t)NT * 32);
        edge_den_kernel<<<(E_IN + 255) / 256, blk, 0, stream>>>(ei_in, ei_in + E_IN, asrc0a, adst0t, den, E_IN);
        edge_agg_kernel<<<(E_IN + 255) / 256, blk, 0, stream>>>(ei_in, ei_in + E_IN, h_a, asrc0a, adst0t, den, agg_t0, E_IN);

        // rel1: tx -> addr over ei_output (h_a now dead; agg_a reuses its region)
        zero(den, (size_t)NA * 4);
        zero(agg_a, (size_t)NA * 32);
        edge_den_kernel<<<(E_OUT + 255) / 256, blk, 0, stream>>>(ei_out, ei_out + E_OUT, asrc1t, adst1a, den, E_OUT);
        edge_agg_kernel<<<(E_OUT + 255) / 256, blk, 0, stream>>>(ei_out, ei_out + E_OUT, h_t, asrc1t, adst1a, den, agg_a, E_OUT);

        // rel2: tx -> tx over ei_spent
        zero(den, (size_t)NT * 4);
        zero(agg_t2, (size_t)NT * 32);
        edge_den_kernel<<<(E_SP + 255) / 256, blk, 0, stream>>>(ei_sp, ei_sp + E_SP, asrc2t, adst2t, den, E_SP);
        edge_agg_kernel<<<(E_SP + 255) / 256, blk, 0, stream>>>(ei_sp, ei_sp + E_SP, h_t, asrc2t, adst2t, den, agg_t2, E_SP);

        // semantic attention scores for tx (addr has a single relation -> attn == 1)
        zero(scores, 64);
        score_kernel<<<nbT, blk, 0, stream>>>(agg_t0, klw + l * 1024, klb + l * 32, qv + l * 32, scores + 0, NT);
        score_kernel<<<nbT, blk, 0, stream>>>(agg_t2, klw + l * 1024, klb + l * 32, qv + l * 32, scores + 1, NT);

        combine_addr_kernel<<<nbA, blk, 0, stream>>>(agg_a, xa, ln_ag, ln_ab, NA);
        combine_tx_kernel<<<nbT, blk, 0, stream>>>(agg_t0, agg_t2, xt, scores, ln_tg, ln_tb, NT, 1.0f / (float)NT);
    }

    final_kernel<<<nbA, blk, 0, stream>>>(xa, lin_w, lin_b, out, NA);
}

// Round 3
// 2632.778 us; speedup vs baseline: 7.8579x; 7.8579x over previous
//
#include <hip/hip_runtime.h>
#include <hip/hip_fp16.h>

#define NLAYERS 4

// ---------------- zero fill (int granular, grid-stride) ----------------
__global__ void zero_int_kernel(int* __restrict__ p, long n) {
    long i = (long)blockIdx.x * 256 + threadIdx.x;
    long stride = (long)gridDim.x * 256;
    for (; i < n; i += stride) p[i] = 0;
}

// ---------------- unpack 8 halfs (in a float4) to 8 floats ----------------
__device__ __forceinline__ void unpack8(float4 raw, float* dst) {
    const __half2* h = (const __half2*)&raw;
    #pragma unroll
    for (int j = 0; j < 4; j++) { float2 v = __half22float2(h[j]); dst[2 * j] = v.x; dst[2 * j + 1] = v.y; }
}

// ---------------- encoder: out = relu(x @ W + b), x [n,kin], W [kin,32] ----------------
__global__ void enc_kernel(const float* __restrict__ x, const float* __restrict__ W,
                           const float* __restrict__ b, float* __restrict__ out,
                           int n, int kin) {
    __shared__ float sW[53 * 32];
    __shared__ float sb[32];
    __shared__ float sx[8][56];
    int tid = threadIdx.x;
    for (int i = tid; i < kin * 32; i += 256) sW[i] = W[i];
    if (tid < 32) sb[tid] = b[tid];
    int local = tid >> 5, f = tid & 31;
    int node = blockIdx.x * 8 + local;
    __syncthreads();
    if (node < n) {
        for (int k = f; k < kin; k += 32) sx[local][k] = x[(size_t)node * kin + k];
    }
    __syncthreads();
    if (node >= n) return;
    float acc = sb[f];
    for (int k = 0; k < kin; k++) acc += sx[local][k] * sW[k * 32 + f];
    out[(size_t)node * 32 + f] = fmaxf(acc, 0.0f);
}

// ---------------- projection for addr: h(half) = x@W+b; asrc0/adst1 per head ----------------
__global__ void proj_addr_kernel(const float* __restrict__ x,
                                 const float* __restrict__ W, const float* __restrict__ b,
                                 const float* __restrict__ a0, const float* __restrict__ a1,
                                 __half* __restrict__ h, float* __restrict__ o0,
                                 float* __restrict__ o1, int n) {
    __shared__ float sW[1024];
    __shared__ float sv[3][32];
    __shared__ float sx[8][33];
    __shared__ float sh[8][33];
    int tid = threadIdx.x;
    for (int i = tid; i < 1024; i += 256) sW[i] = W[i];
    if (tid < 32) { sv[0][tid] = b[tid]; sv[1][tid] = a0[tid]; sv[2][tid] = a1[tid]; }
    int local = tid >> 5, f = tid & 31;
    int node = blockIdx.x * 8 + local;
    __syncthreads();
    if (node < n) sx[local][f] = x[(size_t)node * 32 + f];
    __syncthreads();
    if (node < n) {
        float acc = sv[0][f];
        #pragma unroll
        for (int k = 0; k < 32; k++) acc += sx[local][k] * sW[k * 32 + f];
        h[(size_t)node * 32 + f] = __float2half(acc);
        sh[local][f] = acc;
    }
    __syncthreads();
    if (node < n && f < 8) {
        int vec = f >> 2, head = f & 3;
        const float* av = sv[1 + vec];
        float dsum = 0.f;
        #pragma unroll
        for (int dd = 0; dd < 8; dd++) dsum += sh[local][head * 8 + dd] * av[head * 8 + dd];
        (vec == 0 ? o0 : o1)[(size_t)node * 4 + head] = dsum;
    }
}

// ---------------- projection for tx: h(half) + 4 attention vectors ----------------
__global__ void proj_tx_kernel(const float* __restrict__ x,
                               const float* __restrict__ W, const float* __restrict__ b,
                               const float* __restrict__ a0, const float* __restrict__ a1,
                               const float* __restrict__ a2, const float* __restrict__ a3,
                               __half* __restrict__ h,
                               float* __restrict__ o0, float* __restrict__ o1,
                               float* __restrict__ o2, float* __restrict__ o3, int n) {
    __shared__ float sW[1024];
    __shared__ float sv[5][32];
    __shared__ float sx[8][33];
    __shared__ float sh[8][33];
    int tid = threadIdx.x;
    for (int i = tid; i < 1024; i += 256) sW[i] = W[i];
    if (tid < 32) {
        sv[0][tid] = b[tid]; sv[1][tid] = a0[tid]; sv[2][tid] = a1[tid];
        sv[3][tid] = a2[tid]; sv[4][tid] = a3[tid];
    }
    int local = tid >> 5, f = tid & 31;
    int node = blockIdx.x * 8 + local;
    __syncthreads();
    if (node < n) sx[local][f] = x[(size_t)node * 32 + f];
    __syncthreads();
    if (node < n) {
        float acc = sv[0][f];
        #pragma unroll
        for (int k = 0; k < 32; k++) acc += sx[local][k] * sW[k * 32 + f];
        h[(size_t)node * 32 + f] = __float2half(acc);
        sh[local][f] = acc;
    }
    __syncthreads();
    if (node < n && f < 16) {
        int vec = f >> 2, head = f & 3;
        const float* av = sv[1 + vec];
        float dsum = 0.f;
        #pragma unroll
        for (int dd = 0; dd < 8; dd++) dsum += sh[local][head * 8 + dd] * av[head * 8 + dd];
        float* op = vec == 0 ? o0 : vec == 1 ? o1 : vec == 2 ? o2 : o3;
        op[(size_t)node * 4 + head] = dsum;
    }
}

// ================= CSR build =================
__global__ void hist_kernel(const int* __restrict__ di, int* __restrict__ deg, int E) {
    int e = blockIdx.x * 256 + threadIdx.x;
    if (e < E) atomicAdd(&deg[di[e]], 1);
}

// per-block (1024 elems) exclusive scan; block total -> bsum
__global__ void scan1_kernel(const int* __restrict__ deg, int* __restrict__ rowptr,
                             int* __restrict__ bsum, int n) {
    __shared__ int lds[256];
    int tid = threadIdx.x;
    int base = blockIdx.x * 1024;
    int v[4];
    int mysum = 0;
    #pragma unroll
    for (int j = 0; j < 4; j++) {
        int idx = base + tid * 4 + j;
        v[j] = (idx < n) ? deg[idx] : 0;
        mysum += v[j];
    }
    lds[tid] = mysum;
    __syncthreads();
    for (int off = 1; off < 256; off <<= 1) {
        int t = (tid >= off) ? lds[tid - off] : 0;
        __syncthreads();
        lds[tid] += t;
        __syncthreads();
    }
    int excl = lds[tid] - mysum;
    if (tid == 255) bsum[blockIdx.x] = lds[tid];
    int run = excl;
    #pragma unroll
    for (int j = 0; j < 4; j++) {
        int idx = base + tid * 4 + j;
        if (idx < n) rowptr[idx] = run;
        run += v[j];
    }
}

// single-block exclusive scan of block sums (nb <= 1024)
__global__ void scan2_kernel(int* __restrict__ bsum, int nb) {
    __shared__ int lds[1024];
    int tid = threadIdx.x;
    int v = (tid < nb) ? bsum[tid] : 0;
    lds[tid] = v;
    __syncthreads();
    for (int off = 1; off < 1024; off <<= 1) {
        int t = (tid >= off) ? lds[tid - off] : 0;
        __syncthreads();
        lds[tid] += t;
        __syncthreads();
    }
    if (tid < nb) bsum[tid] = lds[tid] - v;
}

// add block offsets; copy into cursor; write rowptr[n]=E
__global__ void scan3_kernel(int* __restrict__ rowptr, const int* __restrict__ bsum,
                             int* __restrict__ cursor, int n, int E) {
    int i = blockIdx.x * 256 + threadIdx.x;
    if (i < n) {
        int r = rowptr[i] + bsum[i >> 10];
        rowptr[i] = r;
        cursor[i] = r;
    }
    if (i == 0) rowptr[n] = E;
}

__global__ void scatter_kernel(const int* __restrict__ si, const int* __restrict__ di,
                               int* __restrict__ cursor, int* __restrict__ col, int E) {
    int e = blockIdx.x * 256 + threadIdx.x;
    if (e >= E) return;
    int pos = atomicAdd(&cursor[di[e]], 1);
    col[pos] = si[e];
}

// ================= CSR aggregation: 32 lanes per dst (lane = feature) =================
// agg[dst,f] = (sum_e exp(leaky(asrc[s,head]+adst[dst,head])) * h[s,f]) / (den + 1e-16)
__global__ void csr_agg_kernel(const int* __restrict__ rowptr, const int* __restrict__ col,
                               const __half* __restrict__ h,
                               const float* __restrict__ asrc, const float* __restrict__ adst,
                               __half* __restrict__ agg, int n_dst) {
    int tid = threadIdx.x;
    int f = tid & 31;
    int local = tid >> 5;
    int dst = blockIdx.x * 8 + local;
    if (dst >= n_dst) return;
    int head = f >> 3;
    float ad = adst[(size_t)dst * 4 + head];
    int e0 = rowptr[dst], e1 = rowptr[dst + 1];
    float acc = 0.f, den = 0.f;
    for (int e = e0; e < e1; e++) {
        int s = col[e];
        float as_ = asrc[(size_t)s * 4 + head];
        float t = as_ + ad;
        t = t > 0.f ? t : 0.2f * t;
        float ex = __expf(t);
        den += ex;
        acc += ex * __half2float(h[(size_t)s * 32 + f]);
    }
    agg[(size_t)dst * 32 + f] = __float2half(acc / (den + 1e-16f));
}

// ---------------- semantic score: score += sum_n q . tanh(relu(agg[n]) @ kw + kb) ----------------
__global__ void score_kernel(const __half* __restrict__ agg, const float* __restrict__ kw,
                             const float* __restrict__ kb, const float* __restrict__ q,
                             float* __restrict__ score, int n) {
    __shared__ float sW[1024];
    __shared__ float sb[32];
    __shared__ float sq[32];
    int tid = threadIdx.x;
    for (int i = tid; i < 1024; i += 256) sW[i] = kw[i];
    if (tid < 32) { sb[tid] = kb[tid]; sq[tid] = q[tid]; }
    __syncthreads();
    int node = blockIdx.x * 256 + tid;
    float acc = 0.f;
    if (node < n) {
        float xr[32];
        const float4* p = (const float4*)(agg + (size_t)node * 32);
        #pragma unroll
        for (int i = 0; i < 4; i++) unpack8(p[i], xr + 8 * i);
        #pragma unroll
        for (int k = 0; k < 32; k++) xr[k] = fmaxf(xr[k], 0.f);
        for (int ff = 0; ff < 32; ff++) {
            float y = sb[ff];
            #pragma unroll
            for (int k = 0; k < 32; k++) y += xr[k] * sW[k * 32 + ff];
            acc += sq[ff] * tanhf(y);
        }
    }
    #pragma unroll
    for (int off = 32; off > 0; off >>= 1) acc += __shfl_down(acc, off, 64);
    if ((tid & 63) == 0) unsafeAtomicAdd(score, acc);
}

// ---------------- combine addr: xa = LN(relu(agg) + xa) ----------------
__global__ void combine_addr_kernel(const __half* __restrict__ agg, float* __restrict__ xa,
                                    const float* __restrict__ g, const float* __restrict__ bt, int n) {
    int node = blockIdx.x * 256 + threadIdx.x;
    if (node >= n) return;
    float v[32];
    const float4* ap = (const float4*)(agg + (size_t)node * 32);
    float4* xp = (float4*)(xa + (size_t)node * 32);
    #pragma unroll
    for (int i = 0; i < 4; i++) unpack8(ap[i], v + 8 * i);
    #pragma unroll
    for (int i = 0; i < 8; i++) {
        float4 x = xp[i];
        v[4 * i + 0] = fmaxf(v[4 * i + 0], 0.f) + x.x;
        v[4 * i + 1] = fmaxf(v[4 * i + 1], 0.f) + x.y;
        v[4 * i + 2] = fmaxf(v[4 * i + 2], 0.f) + x.z;
        v[4 * i + 3] = fmaxf(v[4 * i + 3], 0.f) + x.w;
    }
    float m = 0.f;
    #pragma unroll
    for (int f = 0; f < 32; f++) m += v[f];
    m *= (1.f / 32.f);
    float var = 0.f;
    #pragma unroll
    for (int f = 0; f < 32; f++) { float dd = v[f] - m; var += dd * dd; }
    var *= (1.f / 32.f);
    float inv = 1.f / sqrtf(var + 1e-5f);
    #pragma unroll
    for (int i = 0; i < 8; i++) {
        float4 o;
        o.x = (v[4 * i + 0] - m) * inv * g[4 * i + 0] + bt[4 * i + 0];
        o.y = (v[4 * i + 1] - m) * inv * g[4 * i + 1] + bt[4 * i + 1];
        o.z = (v[4 * i + 2] - m) * inv * g[4 * i + 2] + bt[4 * i + 2];
        o.w = (v[4 * i + 3] - m) * inv * g[4 * i + 3] + bt[4 * i + 3];
        xp[i] = o;
    }
}

// ---------------- combine tx: xt = LN(relu(w0*relu(agg0)+w2*relu(agg2)) + xt) ----------------
__global__ void combine_tx_kernel(const __half* __restrict__ agg0, const __half* __restrict__ agg2,
                                  float* __restrict__ xt, const float* __restrict__ scores,
                                  const float* __restrict__ g, const float* __restrict__ bt,
                                  int n, float invN) {
    int node = blockIdx.x * 256 + threadIdx.x;
    if (node >= n) return;
    float s0 = scores[0] * invN, s2 = scores[1] * invN;
    float mx = fmaxf(s0, s2);
    float e0 = __expf(s0 - mx), e2 = __expf(s2 - mx);
    float inv_s = 1.f / (e0 + e2);
    float w0 = e0 * inv_s, w2 = e2 * inv_s;
    float va[32], vc[32];
    const float4* a0p = (const float4*)(agg0 + (size_t)node * 32);
    const float4* a2p = (const float4*)(agg2 + (size_t)node * 32);
    float4* xp = (float4*)(xt + (size_t)node * 32);
    #pragma unroll
    for (int i = 0; i < 4; i++) { unpack8(a0p[i], va + 8 * i); unpack8(a2p[i], vc + 8 * i); }
    float v[32];
    #pragma unroll
    for (int i = 0; i < 8; i++) {
        float4 x = xp[i];
        v[4 * i + 0] = fmaxf(w0 * fmaxf(va[4 * i + 0], 0.f) + w2 * fmaxf(vc[4 * i + 0], 0.f), 0.f) + x.x;
        v[4 * i + 1] = fmaxf(w0 * fmaxf(va[4 * i + 1], 0.f) + w2 * fmaxf(vc[4 * i + 1], 0.f), 0.f) + x.y;
        v[4 * i + 2] = fmaxf(w0 * fmaxf(va[4 * i + 2], 0.f) + w2 * fmaxf(vc[4 * i + 2], 0.f), 0.f) + x.z;
        v[4 * i + 3] = fmaxf(w0 * fmaxf(va[4 * i + 3], 0.f) + w2 * fmaxf(vc[4 * i + 3], 0.f), 0.f) + x.w;
    }
    float m = 0.f;
    #pragma unroll
    for (int f = 0; f < 32; f++) m += v[f];
    m *= (1.f / 32.f);
    float var = 0.f;
    #pragma unroll
    for (int f = 0; f < 32; f++) { float dd = v[f] - m; var += dd * dd; }
    var *= (1.f / 32.f);
    float inv = 1.f / sqrtf(var + 1e-5f);
    #pragma unroll
    for (int i = 0; i < 8; i++) {
        float4 o;
        o.x = (v[4 * i + 0] - m) * inv * g[4 * i + 0] + bt[4 * i + 0];
        o.y = (v[4 * i + 1] - m) * inv * g[4 * i + 1] + bt[4 * i + 1];
        o.z = (v[4 * i + 2] - m) * inv * g[4 * i + 2] + bt[4 * i + 2];
        o.w = (v[4 * i + 3] - m) * inv * g[4 * i + 3] + bt[4 * i + 3];
        xp[i] = o;
    }
}

// ---------------- final: out = xa @ lin_w + lin_b ----------------
__global__ void final_kernel(const float* __restrict__ xa, const float* __restrict__ w,
                             const float* __restrict__ b, float* __restrict__ out, int n) {
    __shared__ float sw[64];
    __shared__ float sb2[2];
    if (threadIdx.x < 64) sw[threadIdx.x] = w[threadIdx.x];
    if (threadIdx.x < 2) sb2[threadIdx.x] = b[threadIdx.x];
    __syncthreads();
    int node = blockIdx.x * 256 + threadIdx.x;
    if (node >= n) return;
    float a0 = sb2[0], a1 = sb2[1];
    const float* xr = xa + (size_t)node * 32;
    #pragma unroll
    for (int k = 0; k < 32; k++) {
        float xv = xr[k];
        a0 += xv * sw[k * 2 + 0];
        a1 += xv * sw[k * 2 + 1];
    }
    out[(size_t)node * 2 + 0] = a0;
    out[(size_t)node * 2 + 1] = a1;
}

extern "C" void kernel_launch(void* const* d_in, const int* in_sizes, int n_in,
                              void* d_out, int out_size, void* d_ws, size_t ws_size,
                              hipStream_t stream) {
    const float* x_addr = (const float*)d_in[0];
    const float* x_tx   = (const float*)d_in[1];
    const int* ei_in    = (const int*)d_in[2];
    const int* ei_out   = (const int*)d_in[3];
    const int* ei_sp    = (const int*)d_in[4];
    const float* enc_w_addr = (const float*)d_in[5];
    const float* enc_b_addr = (const float*)d_in[6];
    const float* enc_w_tx   = (const float*)d_in[7];
    const float* enc_b_tx   = (const float*)d_in[8];
    const float* ln_ag = (const float*)d_in[9];
    const float* ln_ab = (const float*)d_in[10];
    const float* ln_tg = (const float*)d_in[11];
    const float* ln_tb = (const float*)d_in[12];
    const float* pw_a = (const float*)d_in[13];
    const float* pb_a = (const float*)d_in[14];
    const float* pw_t = (const float*)d_in[15];
    const float* pb_t = (const float*)d_in[16];
    const float* att_src = (const float*)d_in[17];
    const float* att_dst = (const float*)d_in[18];
    const float* klw = (const float*)d_in[19];
    const float* klb = (const float*)d_in[20];
    const float* qv  = (const float*)d_in[21];
    const float* lin_w = (const float*)d_in[22];
    const float* lin_b = (const float*)d_in[23];
    float* out = (float*)d_out;

    const int NA = in_sizes[0] / 53;
    const int NT = in_sizes[1] / 6;
    const int E_IN = in_sizes[2] / 2;
    const int E_OUT = in_sizes[3] / 2;
    const int E_SP = in_sizes[4] / 2;
    const int NMAX = NA > NT ? NA : NT;

    // ---- workspace layout (float units, 256B aligned per buffer) ----
    size_t off = 0;
    float* base = (float*)d_ws;
    auto alloc = [&](size_t nfloats) {
        float* p = base + off;
        off += (nfloats + 63) & ~(size_t)63;
        return p;
    };
    float* xa      = alloc((size_t)NA * 32);
    float* xt      = alloc((size_t)NT * 32);
    float* agg_a_f = alloc((size_t)NA * 16);   // fp16 agg for addr; aliases h_a
    float* agg_t0f = alloc((size_t)NT * 16);   // fp16
    float* agg_t2f = alloc((size_t)NT * 16);   // fp16
    float* h_t_f   = alloc((size_t)NT * 16);   // fp16
    float* asrc0a  = alloc((size_t)NA * 4);
    float* adst1a  = alloc((size_t)NA * 4);
    float* asrc1t  = alloc((size_t)NT * 4);
    float* adst0t  = alloc((size_t)NT * 4);
    float* asrc2t  = alloc((size_t)NT * 4);
    float* adst2t  = alloc((size_t)NT * 4);
    int* rowptr0   = (int*)alloc((size_t)NT + 64);
    int* rowptr1   = (int*)alloc((size_t)NA + 64);
    int* rowptr2   = (int*)alloc((size_t)NT + 64);
    int* col0      = (int*)alloc((size_t)E_IN);
    int* col1      = (int*)alloc((size_t)E_OUT);
    int* col2      = (int*)alloc((size_t)E_SP);
    int* tmp       = (int*)alloc((size_t)NMAX);   // deg, then cursor
    int* bsum      = (int*)alloc(1088);
    float* scores  = alloc(64);

    __half* agg_a  = (__half*)agg_a_f;
    __half* agg_t0 = (__half*)agg_t0f;
    __half* agg_t2 = (__half*)agg_t2f;
    __half* h_t    = (__half*)h_t_f;
    __half* h_a    = (__half*)agg_a_f;   // alias: h_a dead before agg_a written (rel1)

    dim3 blk(256);
    int nbA8 = (NA + 7) / 8, nbT8 = (NT + 7) / 8;
    int nbA = (NA + 255) / 256, nbT = (NT + 255) / 256;

    // ---- CSR build (once; reused by all 4 layers) ----
    auto build_csr = [&](const int* si, const int* di, int n_dst, int E,
                         int* rowptr, int* colx) {
        int nb = (n_dst + 1023) / 1024;
        zero_int_kernel<<<(n_dst + 255) / 256, blk, 0, stream>>>(tmp, n_dst);
        hist_kernel<<<(E + 255) / 256, blk, 0, stream>>>(di, tmp, E);
        scan1_kernel<<<nb, blk, 0, stream>>>(tmp, rowptr, bsum, n_dst);
        scan2_kernel<<<1, 1024, 0, stream>>>(bsum, nb);
        scan3_kernel<<<(n_dst + 255) / 256, blk, 0, stream>>>(rowptr, bsum, tmp, n_dst, E);
        scatter_kernel<<<(E + 255) / 256, blk, 0, stream>>>(si, di, tmp, colx, E);
    };
    build_csr(ei_in,  ei_in  + E_IN,  NT, E_IN,  rowptr0, col0);
    build_csr(ei_out, ei_out + E_OUT, NA, E_OUT, rowptr1, col1);
    build_csr(ei_sp,  ei_sp  + E_SP,  NT, E_SP,  rowptr2, col2);

    enc_kernel<<<nbA8, blk, 0, stream>>>(x_addr, enc_w_addr, enc_b_addr, xa, NA, 53);
    enc_kernel<<<nbT8, blk, 0, stream>>>(x_tx, enc_w_tx, enc_b_tx, xt, NT, 6);

    for (int l = 0; l < NLAYERS; l++) {
        const float* W_a = pw_a + l * 1024; const float* B_a = pb_a + l * 32;
        const float* W_t = pw_t + l * 1024; const float* B_t = pb_t + l * 32;
        const float* as0 = att_src + (l * 3 + 0) * 32;
        const float* as1 = att_src + (l * 3 + 1) * 32;
        const float* as2 = att_src + (l * 3 + 2) * 32;
        const float* ad0 = att_dst + (l * 3 + 0) * 32;
        const float* ad1 = att_dst + (l * 3 + 1) * 32;
        const float* ad2 = att_dst + (l * 3 + 2) * 32;

        proj_addr_kernel<<<nbA8, blk, 0, stream>>>(xa, W_a, B_a, as0, ad1, h_a, asrc0a, adst1a, NA);
        proj_tx_kernel<<<nbT8, blk, 0, stream>>>(xt, W_t, B_t, as1, ad0, as2, ad2,
                                                 h_t, asrc1t, adst0t, asrc2t, adst2t, NT);

        // rel0: addr -> tx (reads h_a, writes agg_t0)
        csr_agg_kernel<<<nbT8, blk, 0, stream>>>(rowptr0, col0, h_a, asrc0a, adst0t, agg_t0, NT);
        // rel1: tx -> addr (h_a dead now; agg_a overwrites its region)
        csr_agg_kernel<<<nbA8, blk, 0, stream>>>(rowptr1, col1, h_t, asrc1t, adst1a, agg_a, NA);
        // rel2: tx -> tx
        csr_agg_kernel<<<nbT8, blk, 0, stream>>>(rowptr2, col2, h_t, asrc2t, adst2t, agg_t2, NT);

        // semantic attention scores for tx (addr has one relation -> weight 1)
        zero_int_kernel<<<1, blk, 0, stream>>>((int*)scores, 8);
        score_kernel<<<nbT, blk, 0, stream>>>(agg_t0, klw + l * 1024, klb + l * 32, qv + l * 32, scores + 0, NT);
        score_kernel<<<nbT, blk, 0, stream>>>(agg_t2, klw + l * 1024, klb + l * 32, qv + l * 32, scores + 1, NT);

        combine_addr_kernel<<<nbA, blk, 0, stream>>>(agg_a, xa, ln_ag, ln_ab, NA);
        combine_tx_kernel<<<nbT, blk, 0, stream>>>(agg_t0, agg_t2, xt, scores, ln_tg, ln_tb, NT, 1.0f / (float)NT);
    }

    final_kernel<<<nbA, blk, 0, stream>>>(xa, lin_w, lin_b, out, NA);
}

// Round 4
// 1880.970 us; speedup vs baseline: 10.9987x; 1.3997x over previous
//
#include <hip/hip_runtime.h>
#include <hip/hip_fp16.h>

#define NLAYERS 4

// ---------------- zero fill ----------------
__global__ void zero_int_kernel(int* __restrict__ p, long n) {
    long i = (long)blockIdx.x * 256 + threadIdx.x;
    long stride = (long)gridDim.x * 256;
    for (; i < n; i += stride) p[i] = 0;
}

__device__ __forceinline__ void unpack8(float4 raw, float* dst) {
    const __half2* h = (const __half2*)&raw;
    #pragma unroll
    for (int j = 0; j < 4; j++) { float2 v = __half22float2(h[j]); dst[2 * j] = v.x; dst[2 * j + 1] = v.y; }
}

__device__ __forceinline__ float fast_tanh(float y) {
    y = fminf(fmaxf(y, -15.f), 15.f);
    float t = __expf(2.f * y);
    return (t - 1.f) / (t + 1.f);
}

// ================= merged CSR build over concatenated dst space =================
// node space: [0,NT) rel0 dsts | [NT,NT+NA) rel1 dsts | [NT+NA,NT+NA+NT) rel2 dsts
__global__ void hist_kernel(const int* __restrict__ ei_in, const int* __restrict__ ei_out,
                            const int* __restrict__ ei_sp, int E_IN, int E_OUT, int E_SP,
                            int NT, int NA, int* __restrict__ deg) {
    int e = blockIdx.x * 256 + threadIdx.x;
    int d, base;
    if (e < E_IN) { d = ei_in[E_IN + e]; base = 0; }
    else if (e < E_IN + E_OUT) { int i = e - E_IN; d = ei_out[E_OUT + i]; base = NT; }
    else if (e < E_IN + E_OUT + E_SP) { int i = e - E_IN - E_OUT; d = ei_sp[E_SP + i]; base = NT + NA; }
    else return;
    atomicAdd(&deg[base + d], 1);
}

__global__ void scan1_kernel(const int* __restrict__ deg, int* __restrict__ rowptr,
                             int* __restrict__ bsum, int n) {
    __shared__ int lds[256];
    int tid = threadIdx.x;
    int base = blockIdx.x * 1024;
    int v[4];
    int mysum = 0;
    #pragma unroll
    for (int j = 0; j < 4; j++) {
        int idx = base + tid * 4 + j;
        v[j] = (idx < n) ? deg[idx] : 0;
        mysum += v[j];
    }
    lds[tid] = mysum;
    __syncthreads();
    for (int off = 1; off < 256; off <<= 1) {
        int t = (tid >= off) ? lds[tid - off] : 0;
        __syncthreads();
        lds[tid] += t;
        __syncthreads();
    }
    int excl = lds[tid] - mysum;
    if (tid == 255) bsum[blockIdx.x] = lds[tid];
    int run = excl;
    #pragma unroll
    for (int j = 0; j < 4; j++) {
        int idx = base + tid * 4 + j;
        if (idx < n) rowptr[idx] = run;
        run += v[j];
    }
}

__global__ void scan2_kernel(int* __restrict__ bsum, int nb) {
    __shared__ int lds[1024];
    int tid = threadIdx.x;
    int v = (tid < nb) ? bsum[tid] : 0;
    lds[tid] = v;
    __syncthreads();
    for (int off = 1; off < 1024; off <<= 1) {
        int t = (tid >= off) ? lds[tid - off] : 0;
        __syncthreads();
        lds[tid] += t;
        __syncthreads();
    }
    if (tid < nb) bsum[tid] = lds[tid] - v;
}

__global__ void scan3_kernel(int* __restrict__ rowptr, const int* __restrict__ bsum,
                             int* __restrict__ cursor, int n, int E) {
    int i = blockIdx.x * 256 + threadIdx.x;
    if (i < n) {
        int r = rowptr[i] + bsum[i >> 10];
        rowptr[i] = r;
        cursor[i] = r;
    }
    if (i == 0) rowptr[n] = E;
}

__global__ void scatter_kernel(const int* __restrict__ ei_in, const int* __restrict__ ei_out,
                               const int* __restrict__ ei_sp, int E_IN, int E_OUT, int E_SP,
                               int NT, int NA, int* __restrict__ cursor, int* __restrict__ col) {
    int e = blockIdx.x * 256 + threadIdx.x;
    int s, d, base;
    if (e < E_IN) { s = ei_in[e]; d = ei_in[E_IN + e]; base = 0; }
    else if (e < E_IN + E_OUT) { int i = e - E_IN; s = ei_out[i]; d = ei_out[E_OUT + i]; base = NT; }
    else if (e < E_IN + E_OUT + E_SP) { int i = e - E_IN - E_OUT; s = ei_sp[i]; d = ei_sp[E_SP + i]; base = NT + NA; }
    else return;
    int pos = atomicAdd(&cursor[base + d], 1);
    col[pos] = s;
}

// ================= fused encoder + layer-0 projection =================
// addr: x[n,53] -> xa = relu(x@We+be); h = half(xa@Wp+bp); attention dots
__global__ void encproj_addr_kernel(const float* __restrict__ x,
                                    const float* __restrict__ We, const float* __restrict__ be,
                                    const float* __restrict__ Wp, const float* __restrict__ bp,
                                    const float* __restrict__ a0, const float* __restrict__ a1,
                                    float* __restrict__ xa, __half* __restrict__ h,
                                    float* __restrict__ o0, float* __restrict__ o1, int n) {
    __shared__ float sWe[53 * 32];
    __shared__ float sW[1024];
    __shared__ float sv[3][32];
    __shared__ float sbp[32];
    __shared__ float sx[8][56];
    __shared__ float sh[8][33];
    int tid = threadIdx.x;
    for (int i = tid; i < 53 * 32; i += 256) sWe[i] = We[i];
    for (int i = tid; i < 1024; i += 256) sW[i] = Wp[i];
    if (tid < 32) { sv[0][tid] = be[tid]; sv[1][tid] = a0[tid]; sv[2][tid] = a1[tid]; sbp[tid] = bp[tid]; }
    int local = tid >> 5, f = tid & 31;
    int node = blockIdx.x * 8 + local;
    if (node < n) {
        for (int k = f; k < 53; k += 32) sx[local][k] = x[(size_t)node * 53 + k];
    }
    __syncthreads();
    float xe = 0.f;
    if (node < n) {
        float acc = sv[0][f];
        for (int k = 0; k < 53; k++) acc += sx[local][k] * sWe[k * 32 + f];
        xe = fmaxf(acc, 0.f);
        xa[(size_t)node * 32 + f] = xe;
    }
    sh[local][f] = xe;
    __syncthreads();
    float accp = 0.f;
    if (node < n) {
        accp = sbp[f];
        #pragma unroll
        for (int k = 0; k < 32; k++) accp += sh[local][k] * sW[k * 32 + f];
        h[(size_t)node * 32 + f] = __float2half(accp);
    }
    __syncthreads();
    sh[local][f] = accp;
    __syncthreads();
    if (node < n && f < 8) {
        int vec = f >> 2, head = f & 3;
        const float* av = sv[1 + vec];
        float dsum = 0.f;
        #pragma unroll
        for (int dd = 0; dd < 8; dd++) dsum += sh[local][head * 8 + dd] * av[head * 8 + dd];
        (vec == 0 ? o0 : o1)[(size_t)node * 4 + head] = dsum;
    }
}

// tx: x[n,6], 4 attention vectors
__global__ void encproj_tx_kernel(const float* __restrict__ x,
                                  const float* __restrict__ We, const float* __restrict__ be,
                                  const float* __restrict__ Wp, const float* __restrict__ bp,
                                  const float* __restrict__ a0, const float* __restrict__ a1,
                                  const float* __restrict__ a2, const float* __restrict__ a3,
                                  float* __restrict__ xt, __half* __restrict__ h,
                                  float* __restrict__ o0, float* __restrict__ o1,
                                  float* __restrict__ o2, float* __restrict__ o3, int n) {
    __shared__ float sWe[6 * 32];
    __shared__ float sW[1024];
    __shared__ float sv[5][32];
    __shared__ float sbp[32];
    __shared__ float sx[8][8];
    __shared__ float sh[8][33];
    int tid = threadIdx.x;
    for (int i = tid; i < 6 * 32; i += 256) sWe[i] = We[i];
    for (int i = tid; i < 1024; i += 256) sW[i] = Wp[i];
    if (tid < 32) {
        sv[0][tid] = be[tid]; sv[1][tid] = a0[tid]; sv[2][tid] = a1[tid];
        sv[3][tid] = a2[tid]; sv[4][tid] = a3[tid]; sbp[tid] = bp[tid];
    }
    int local = tid >> 5, f = tid & 31;
    int node = blockIdx.x * 8 + local;
    if (node < n && f < 6) sx[local][f] = x[(size_t)node * 6 + f];
    __syncthreads();
    float xe = 0.f;
    if (node < n) {
        float acc = sv[0][f];
        #pragma unroll
        for (int k = 0; k < 6; k++) acc += sx[local][k] * sWe[k * 32 + f];
        xe = fmaxf(acc, 0.f);
        xt[(size_t)node * 32 + f] = xe;
    }
    sh[local][f] = xe;
    __syncthreads();
    float accp = 0.f;
    if (node < n) {
        accp = sbp[f];
        #pragma unroll
        for (int k = 0; k < 32; k++) accp += sh[local][k] * sW[k * 32 + f];
        h[(size_t)node * 32 + f] = __float2half(accp);
    }
    __syncthreads();
    sh[local][f] = accp;
    __syncthreads();
    if (node < n && f < 16) {
        int vec = f >> 2, head = f & 3;
        const float* av = sv[1 + vec];
        float dsum = 0.f;
        #pragma unroll
        for (int dd = 0; dd < 8; dd++) dsum += sh[local][head * 8 + dd] * av[head * 8 + dd];
        float* op = vec == 0 ? o0 : vec == 1 ? o1 : vec == 2 ? o2 : o3;
        op[(size_t)node * 4 + head] = dsum;
    }
}

// ================= CSR aggregation, 16 lanes/dst, half2 =================
// rel0 + rel2 merged (both write tx-dst aggs; rel1 separate because agg_a aliases h_a)
__global__ void agg02_kernel(const int* __restrict__ rowptr, const int* __restrict__ col,
                             const __half* __restrict__ h_a, const __half* __restrict__ h_t,
                             const float* __restrict__ asrc0, const float* __restrict__ adst0,
                             const float* __restrict__ asrc2, const float* __restrict__ adst2,
                             __half* __restrict__ agg0, __half* __restrict__ agg2,
                             int NT, int NA) {
    int tid = threadIdx.x;
    long gi = (long)blockIdx.x * 16 + (tid >> 4);
    int lane = tid & 15;
    if (gi >= 2L * NT) return;
    bool r2 = gi >= NT;
    int dst = r2 ? (int)(gi - NT) : (int)gi;
    int rowbase = r2 ? (NT + NA) : 0;
    const __half* h = r2 ? h_t : h_a;
    const float* asrc = r2 ? asrc2 : asrc0;
    const float* adst = r2 ? adst2 : adst0;
    __half* agg = r2 ? agg2 : agg0;
    int head = lane >> 2, f0 = lane * 2;
    float ad = adst[(size_t)dst * 4 + head];
    int e0 = rowptr[rowbase + dst], e1 = rowptr[rowbase + dst + 1];
    float accx = 0.f, accy = 0.f, den = 0.f;
    for (int e = e0; e < e1; e++) {
        int s = col[e];
        float t = asrc[(size_t)s * 4 + head] + ad;
        t = t > 0.f ? t : 0.2f * t;
        float ex = __expf(t);
        den += ex;
        __half2 hv = *(const __half2*)(h + (size_t)s * 32 + f0);
        float2 hf = __half22float2(hv);
        accx += ex * hf.x; accy += ex * hf.y;
    }
    float r = 1.f / (den + 1e-16f);
    __half2 o;
    o.x = __float2half(accx * r);
    o.y = __float2half(accy * r);
    *(__half2*)(agg + (size_t)dst * 32 + f0) = o;
}

__global__ void agg1_kernel(const int* __restrict__ rowptr, const int* __restrict__ col,
                            const __half* __restrict__ h_t,
                            const float* __restrict__ asrc1, const float* __restrict__ adst1,
                            __half* __restrict__ agg, int NT, int NA) {
    int tid = threadIdx.x;
    long gi = (long)blockIdx.x * 16 + (tid >> 4);
    int lane = tid & 15;
    if (gi >= (long)NA) return;
    int dst = (int)gi;
    int rowbase = NT;
    int head = lane >> 2, f0 = lane * 2;
    float ad = adst1[(size_t)dst * 4 + head];
    int e0 = rowptr[rowbase + dst], e1 = rowptr[rowbase + dst + 1];
    float accx = 0.f, accy = 0.f, den = 0.f;
    for (int e = e0; e < e1; e++) {
        int s = col[e];
        float t = asrc1[(size_t)s * 4 + head] + ad;
        t = t > 0.f ? t : 0.2f * t;
        float ex = __expf(t);
        den += ex;
        __half2 hv = *(const __half2*)(h_t + (size_t)s * 32 + f0);
        float2 hf = __half22float2(hv);
        accx += ex * hf.x; accy += ex * hf.y;
    }
    float r = 1.f / (den + 1e-16f);
    __half2 o;
    o.x = __float2half(accx * r);
    o.y = __float2half(accy * r);
    *(__half2*)(agg + (size_t)dst * 32 + f0) = o;
}

// ================= semantic scores for both tx relations, one dispatch =================
__global__ void score2_kernel(const __half* __restrict__ agg0, const __half* __restrict__ agg2,
                              const float* __restrict__ kw, const float* __restrict__ kb,
                              const float* __restrict__ q, float* __restrict__ scoreBase,
                              int n, int nbT) {
    __shared__ float sW[1024];
    __shared__ float sb[32];
    __shared__ float sq[32];
    int tid = threadIdx.x;
    for (int i = tid; i < 1024; i += 256) sW[i] = kw[i];
    if (tid < 32) { sb[tid] = kb[tid]; sq[tid] = q[tid]; }
    __syncthreads();
    int rel = blockIdx.x >= nbT;
    const __half* agg = rel ? agg2 : agg0;
    int node = (blockIdx.x - rel * nbT) * 256 + tid;
    float acc = 0.f;
    if (node < n) {
        float xr[32];
        const float4* p = (const float4*)(agg + (size_t)node * 32);
        #pragma unroll
        for (int i = 0; i < 4; i++) unpack8(p[i], xr + 8 * i);
        #pragma unroll
        for (int k = 0; k < 32; k++) xr[k] = fmaxf(xr[k], 0.f);
        for (int ff = 0; ff < 32; ff++) {
            float y = sb[ff];
            #pragma unroll
            for (int k = 0; k < 32; k++) y += xr[k] * sW[k * 32 + ff];
            acc += sq[ff] * fast_tanh(y);
        }
    }
    #pragma unroll
    for (int off = 32; off > 0; off >>= 1) acc += __shfl_down(acc, off, 64);
    if ((tid & 63) == 0) unsafeAtomicAdd(scoreBase + rel, acc);
}

// ================= fused combine(layer l) + projection(layer l+1) =================
// addr blocks then tx blocks; LN via wave-half shuffles; proj via LDS row
__global__ void combineproj_kernel(
    const __half* __restrict__ agg_a, const __half* __restrict__ agg_t0, const __half* __restrict__ agg_t2,
    float* __restrict__ xa, float* __restrict__ xt,
    const float* __restrict__ ln_ag, const float* __restrict__ ln_ab,
    const float* __restrict__ ln_tg, const float* __restrict__ ln_tb,
    const float* __restrict__ scores, float invNT,
    const float* __restrict__ Wa, const float* __restrict__ Ba,
    const float* __restrict__ Wt, const float* __restrict__ Bt,
    const float* __restrict__ as0, const float* __restrict__ ad1,
    const float* __restrict__ as1, const float* __restrict__ ad0,
    const float* __restrict__ as2, const float* __restrict__ ad2,
    __half* __restrict__ h_a, __half* __restrict__ h_t,
    float* __restrict__ o_as0, float* __restrict__ o_ad1,
    float* __restrict__ o_as1, float* __restrict__ o_ad0,
    float* __restrict__ o_as2, float* __restrict__ o_ad2,
    int NA_, int NT_, int nbA8) {
    __shared__ float sW[1024];
    __shared__ float sv[5][32];
    __shared__ float sbp[32];
    __shared__ float sh[8][33];
    int tid = threadIdx.x;
    bool isA = blockIdx.x < nbA8;
    const float* W = isA ? Wa : Wt;
    for (int i = tid; i < 1024; i += 256) sW[i] = W[i];
    if (tid < 32) {
        sbp[tid] = (isA ? Ba : Bt)[tid];
        sv[1][tid] = (isA ? as0 : as1)[tid];
        sv[2][tid] = (isA ? ad1 : ad0)[tid];
        if (!isA) { sv[3][tid] = as2[tid]; sv[4][tid] = ad2[tid]; }
    }
    int local = tid >> 5, f = tid & 31;
    int n = isA ? NA_ : NT_;
    int node = (isA ? blockIdx.x : blockIdx.x - nbA8) * 8 + local;
    float ln = 0.f;
    if (node < n) {
        float v;
        if (isA) {
            float a = __half2float(agg_a[(size_t)node * 32 + f]);
            v = fmaxf(a, 0.f) + xa[(size_t)node * 32 + f];
        } else {
            float s0 = scores[0] * invNT, s2 = scores[1] * invNT;
            float mx = fmaxf(s0, s2);
            float e0 = __expf(s0 - mx), e2 = __expf(s2 - mx);
            float inv_s = 1.f / (e0 + e2);
            float w0 = e0 * inv_s, w2 = e2 * inv_s;
            float a0 = fmaxf(__half2float(agg_t0[(size_t)node * 32 + f]), 0.f);
            float a2 = fmaxf(__half2float(agg_t2[(size_t)node * 32 + f]), 0.f);
            v = fmaxf(w0 * a0 + w2 * a2, 0.f) + xt[(size_t)node * 32 + f];
        }
        float m = v;
        #pragma unroll
        for (int mask = 1; mask < 32; mask <<= 1) m += __shfl_xor(m, mask, 64);
        m *= (1.f / 32.f);
        float d = v - m;
        float var = d * d;
        #pragma unroll
        for (int mask = 1; mask < 32; mask <<= 1) var += __shfl_xor(var, mask, 64);
        var *= (1.f / 32.f);
        float inv = 1.f / sqrtf(var + 1e-5f);
        ln = d * inv * (isA ? ln_ag : ln_tg)[f] + (isA ? ln_ab : ln_tb)[f];
        (isA ? xa : xt)[(size_t)node * 32 + f] = ln;
    }
    sh[local][f] = ln;
    __syncthreads();
    float accp = 0.f;
    if (node < n) {
        accp = sbp[f];
        #pragma unroll
        for (int k = 0; k < 32; k++) accp += sh[local][k] * sW[k * 32 + f];
        (isA ? h_a : h_t)[(size_t)node * 32 + f] = __float2half(accp);
    }
    __syncthreads();
    sh[local][f] = accp;
    __syncthreads();
    int nvec = isA ? 8 : 16;
    if (node < n && f < nvec) {
        int vec = f >> 2, head = f & 3;
        const float* av = sv[1 + vec];
        float dsum = 0.f;
        #pragma unroll
        for (int dd = 0; dd < 8; dd++) dsum += sh[local][head * 8 + dd] * av[head * 8 + dd];
        float* op;
        if (isA) op = vec == 0 ? o_as0 : o_ad1;
        else op = vec == 0 ? o_as1 : vec == 1 ? o_ad0 : vec == 2 ? o_as2 : o_ad2;
        op[(size_t)node * 4 + head] = dsum;
    }
}

// ================= layer-3 combine_addr + output head =================
__global__ void combine_final_kernel(const __half* __restrict__ agg_a, const float* __restrict__ xa,
                                     const float* __restrict__ g, const float* __restrict__ bt,
                                     const float* __restrict__ lw, const float* __restrict__ lb,
                                     float* __restrict__ out, int n) {
    int tid = threadIdx.x;
    int local = tid >> 5, f = tid & 31;
    int node = blockIdx.x * 8 + local;
    if (node >= n) return;
    float a = __half2float(agg_a[(size_t)node * 32 + f]);
    float v = fmaxf(a, 0.f) + xa[(size_t)node * 32 + f];
    float m = v;
    #pragma unroll
    for (int mask = 1; mask < 32; mask <<= 1) m += __shfl_xor(m, mask, 64);
    m *= (1.f / 32.f);
    float d = v - m;
    float var = d * d;
    #pragma unroll
    for (int mask = 1; mask < 32; mask <<= 1) var += __shfl_xor(var, mask, 64);
    var *= (1.f / 32.f);
    float inv = 1.f / sqrtf(var + 1e-5f);
    float ln = d * inv * g[f] + bt[f];
    float p0 = ln * lw[f * 2 + 0];
    float p1 = ln * lw[f * 2 + 1];
    #pragma unroll
    for (int mask = 1; mask < 32; mask <<= 1) {
        p0 += __shfl_xor(p0, mask, 64);
        p1 += __shfl_xor(p1, mask, 64);
    }
    if (f == 0) {
        out[(size_t)node * 2 + 0] = p0 + lb[0];
        out[(size_t)node * 2 + 1] = p1 + lb[1];
    }
}

extern "C" void kernel_launch(void* const* d_in, const int* in_sizes, int n_in,
                              void* d_out, int out_size, void* d_ws, size_t ws_size,
                              hipStream_t stream) {
    const float* x_addr = (const float*)d_in[0];
    const float* x_tx   = (const float*)d_in[1];
    const int* ei_in    = (const int*)d_in[2];
    const int* ei_out   = (const int*)d_in[3];
    const int* ei_sp    = (const int*)d_in[4];
    const float* enc_w_addr = (const float*)d_in[5];
    const float* enc_b_addr = (const float*)d_in[6];
    const float* enc_w_tx   = (const float*)d_in[7];
    const float* enc_b_tx   = (const float*)d_in[8];
    const float* ln_ag = (const float*)d_in[9];
    const float* ln_ab = (const float*)d_in[10];
    const float* ln_tg = (const float*)d_in[11];
    const float* ln_tb = (const float*)d_in[12];
    const float* pw_a = (const float*)d_in[13];
    const float* pb_a = (const float*)d_in[14];
    const float* pw_t = (const float*)d_in[15];
    const float* pb_t = (const float*)d_in[16];
    const float* att_src = (const float*)d_in[17];
    const float* att_dst = (const float*)d_in[18];
    const float* klw = (const float*)d_in[19];
    const float* klb = (const float*)d_in[20];
    const float* qv  = (const float*)d_in[21];
    const float* lin_w = (const float*)d_in[22];
    const float* lin_b = (const float*)d_in[23];
    float* out = (float*)d_out;

    const int NA = in_sizes[0] / 53;
    const int NT = in_sizes[1] / 6;
    const int E_IN = in_sizes[2] / 2;
    const int E_OUT = in_sizes[3] / 2;
    const int E_SP = in_sizes[4] / 2;
    const int E_TOT = E_IN + E_OUT + E_SP;
    const int NCAT = NT + NA + NT;   // concatenated dst space: rel0 | rel1 | rel2

    // ---- workspace layout (float units, 256B aligned) ----
    size_t off = 0;
    float* base = (float*)d_ws;
    auto alloc = [&](size_t nfloats) {
        float* p = base + off;
        off += (nfloats + 63) & ~(size_t)63;
        return p;
    };
    float* xa      = alloc((size_t)NA * 32);
    float* xt      = alloc((size_t)NT * 32);
    float* agg_a_f = alloc((size_t)NA * 16);   // fp16; aliases h_a (safe: rel0 reads h_a before agg1 writes)
    float* agg_t0f = alloc((size_t)NT * 16);
    float* agg_t2f = alloc((size_t)NT * 16);
    float* h_t_f   = alloc((size_t)NT * 16);
    float* asrc0a  = alloc((size_t)NA * 4);
    float* adst1a  = alloc((size_t)NA * 4);
    float* asrc1t  = alloc((size_t)NT * 4);
    float* adst0t  = alloc((size_t)NT * 4);
    float* asrc2t  = alloc((size_t)NT * 4);
    float* adst2t  = alloc((size_t)NT * 4);
    int* rowptrAll = (int*)alloc((size_t)NCAT + 64);
    int* colAll    = (int*)alloc((size_t)E_TOT);
    // tmp, bsum, scores contiguous so one zero launch covers them all
    size_t tmp_span = ((size_t)NCAT + 63 & ~(size_t)63) + 1088 + 64;
    int* tmp       = (int*)alloc((size_t)NCAT);   // deg, then cursor
    int* bsum      = (int*)alloc(1088);
    float* scores  = alloc(64);                   // 2 per layer

    __half* agg_a  = (__half*)agg_a_f;
    __half* agg_t0 = (__half*)agg_t0f;
    __half* agg_t2 = (__half*)agg_t2f;
    __half* h_t    = (__half*)h_t_f;
    __half* h_a    = (__half*)agg_a_f;

    dim3 blk(256);
    int nbA8 = (NA + 7) / 8, nbT8 = (NT + 7) / 8;
    int nbT = (NT + 255) / 256;
    int nbE = (E_TOT + 255) / 256;
    int nbScan = (NCAT + 1023) / 1024;

    // ---- CSR build (once; reused by all layers) + zero scores ----
    zero_int_kernel<<<2048, blk, 0, stream>>>(tmp, (long)tmp_span);
    hist_kernel<<<nbE, blk, 0, stream>>>(ei_in, ei_out, ei_sp, E_IN, E_OUT, E_SP, NT, NA, tmp);
    scan1_kernel<<<nbScan, blk, 0, stream>>>(tmp, rowptrAll, bsum, NCAT);
    scan2_kernel<<<1, 1024, 0, stream>>>(bsum, nbScan);
    scan3_kernel<<<(NCAT + 255) / 256, blk, 0, stream>>>(rowptrAll, bsum, tmp, NCAT, E_TOT);
    scatter_kernel<<<nbE, blk, 0, stream>>>(ei_in, ei_out, ei_sp, E_IN, E_OUT, E_SP, NT, NA, tmp, colAll);

    // ---- fused encoder + layer-0 projection ----
    encproj_addr_kernel<<<nbA8, blk, 0, stream>>>(
        x_addr, enc_w_addr, enc_b_addr, pw_a, pb_a,
        att_src + 0 * 32, att_dst + 1 * 32,
        xa, h_a, asrc0a, adst1a, NA);
    encproj_tx_kernel<<<nbT8, blk, 0, stream>>>(
        x_tx, enc_w_tx, enc_b_tx, pw_t, pb_t,
        att_src + 1 * 32, att_dst + 0 * 32, att_src + 2 * 32, att_dst + 2 * 32,
        xt, h_t, asrc1t, adst0t, asrc2t, adst2t, NT);

    int nbAgg02 = (2 * NT + 15) / 16;
    int nbAgg1  = (NA + 15) / 16;

    for (int l = 0; l < NLAYERS; l++) {
        bool last = (l == NLAYERS - 1);
        if (!last) {
            // rel0 (reads h_a) + rel2, then rel1 (overwrites h_a region with agg_a)
            agg02_kernel<<<nbAgg02, blk, 0, stream>>>(rowptrAll, colAll, h_a, h_t,
                                                      asrc0a, adst0t, asrc2t, adst2t,
                                                      agg_t0, agg_t2, NT, NA);
            agg1_kernel<<<nbAgg1, blk, 0, stream>>>(rowptrAll, colAll, h_t, asrc1t, adst1a,
                                                    agg_a, NT, NA);
            score2_kernel<<<2 * nbT, blk, 0, stream>>>(agg_t0, agg_t2, klw + l * 1024,
                                                       klb + l * 32, qv + l * 32,
                                                       scores + 2 * l, NT, nbT);
            int lp = l + 1;
            combineproj_kernel<<<nbA8 + nbT8, blk, 0, stream>>>(
                agg_a, agg_t0, agg_t2, xa, xt,
                ln_ag, ln_ab, ln_tg, ln_tb,
                scores + 2 * l, 1.0f / (float)NT,
                pw_a + lp * 1024, pb_a + lp * 32, pw_t + lp * 1024, pb_t + lp * 32,
                att_src + (lp * 3 + 0) * 32, att_dst + (lp * 3 + 1) * 32,
                att_src + (lp * 3 + 1) * 32, att_dst + (lp * 3 + 0) * 32,
                att_src + (lp * 3 + 2) * 32, att_dst + (lp * 3 + 2) * 32,
                h_a, h_t,
                asrc0a, adst1a, asrc1t, adst0t, asrc2t, adst2t,
                NA, NT, nbA8);
        } else {
            // layer 3: only rel1 -> combine_addr -> output head (xt/agg_t*/scores dead)
            agg1_kernel<<<nbAgg1, blk, 0, stream>>>(rowptrAll, colAll, h_t, asrc1t, adst1a,
                                                    agg_a, NT, NA);
            combine_final_kernel<<<nbA8, blk, 0, stream>>>(agg_a, xa, ln_ag, ln_ab,
                                                           lin_w, lin_b, out, NA);
        }
    }
}

// Round 5
// 1552.374 us; speedup vs baseline: 13.3268x; 1.2117x over previous
//
#include <hip/hip_runtime.h>
#include <hip/hip_fp16.h>

#define NLAYERS 4

// ---------------- zero fill ----------------
__global__ void zero_int_kernel(int* __restrict__ p, long n) {
    long i = (long)blockIdx.x * 256 + threadIdx.x;
    long stride = (long)gridDim.x * 256;
    for (; i < n; i += stride) p[i] = 0;
}

__device__ __forceinline__ float fast_tanh(float y) {
    y = fminf(fmaxf(y, -15.f), 15.f);
    float t = __expf(2.f * y);
    return (t - 1.f) / (t + 1.f);
}

// ================= merged CSR build over concatenated dst space =================
// [0,NT) rel0 dsts | [NT,NT+NA) rel1 dsts | [NT+NA,NT+NA+NT) rel2 dsts
__global__ void hist_kernel(const int* __restrict__ ei_in, const int* __restrict__ ei_out,
                            const int* __restrict__ ei_sp, int E_IN, int E_OUT, int E_SP,
                            int NT, int NA, int* __restrict__ deg) {
    int e = blockIdx.x * 256 + threadIdx.x;
    int d, base;
    if (e < E_IN) { d = ei_in[E_IN + e]; base = 0; }
    else if (e < E_IN + E_OUT) { int i = e - E_IN; d = ei_out[E_OUT + i]; base = NT; }
    else if (e < E_IN + E_OUT + E_SP) { int i = e - E_IN - E_OUT; d = ei_sp[E_SP + i]; base = NT + NA; }
    else return;
    atomicAdd(&deg[base + d], 1);
}

__global__ void scan1_kernel(const int* __restrict__ deg, int* __restrict__ rowptr,
                             int* __restrict__ bsum, int n) {
    __shared__ int lds[256];
    int tid = threadIdx.x;
    int base = blockIdx.x * 1024;
    int v[4];
    int mysum = 0;
    #pragma unroll
    for (int j = 0; j < 4; j++) {
        int idx = base + tid * 4 + j;
        v[j] = (idx < n) ? deg[idx] : 0;
        mysum += v[j];
    }
    lds[tid] = mysum;
    __syncthreads();
    for (int off = 1; off < 256; off <<= 1) {
        int t = (tid >= off) ? lds[tid - off] : 0;
        __syncthreads();
        lds[tid] += t;
        __syncthreads();
    }
    int excl = lds[tid] - mysum;
    if (tid == 255) bsum[blockIdx.x] = lds[tid];
    int run = excl;
    #pragma unroll
    for (int j = 0; j < 4; j++) {
        int idx = base + tid * 4 + j;
        if (idx < n) rowptr[idx] = run;
        run += v[j];
    }
}

__global__ void scan2_kernel(int* __restrict__ bsum, int nb) {
    __shared__ int lds[1024];
    int tid = threadIdx.x;
    int v = (tid < nb) ? bsum[tid] : 0;
    lds[tid] = v;
    __syncthreads();
    for (int off = 1; off < 1024; off <<= 1) {
        int t = (tid >= off) ? lds[tid - off] : 0;
        __syncthreads();
        lds[tid] += t;
        __syncthreads();
    }
    if (tid < nb) bsum[tid] = lds[tid] - v;
}

__global__ void scan3_kernel(int* __restrict__ rowptr, const int* __restrict__ bsum,
                             int* __restrict__ cursor, int n, int E) {
    int i = blockIdx.x * 256 + threadIdx.x;
    if (i < n) {
        int r = rowptr[i] + bsum[i >> 10];
        rowptr[i] = r;
        cursor[i] = r;
    }
    if (i == 0) rowptr[n] = E;
}

__global__ void scatter_kernel(const int* __restrict__ ei_in, const int* __restrict__ ei_out,
                               const int* __restrict__ ei_sp, int E_IN, int E_OUT, int E_SP,
                               int NT, int NA, int* __restrict__ cursor, int* __restrict__ col) {
    int e = blockIdx.x * 256 + threadIdx.x;
    int s, d, base;
    if (e < E_IN) { s = ei_in[e]; d = ei_in[E_IN + e]; base = 0; }
    else if (e < E_IN + E_OUT) { int i = e - E_IN; s = ei_out[i]; d = ei_out[E_OUT + i]; base = NT; }
    else if (e < E_IN + E_OUT + E_SP) { int i = e - E_IN - E_OUT; s = ei_sp[i]; d = ei_sp[E_SP + i]; base = NT + NA; }
    else return;
    int pos = atomicAdd(&cursor[base + d], 1);
    col[pos] = s;
}

// ================= fused encoder + layer-0 projection =================
__global__ void encproj_addr_kernel(const float* __restrict__ x,
                                    const float* __restrict__ We, const float* __restrict__ be,
                                    const float* __restrict__ Wp, const float* __restrict__ bp,
                                    const float* __restrict__ a0, const float* __restrict__ a1,
                                    float* __restrict__ xa, __half* __restrict__ h,
                                    float* __restrict__ o0, float* __restrict__ o1, int n) {
    __shared__ float sWe[53 * 32];
    __shared__ float sW[1024];
    __shared__ float sv[3][32];
    __shared__ float sbp[32];
    __shared__ float sx[8][56];
    __shared__ float sh[8][33];
    int tid = threadIdx.x;
    for (int i = tid; i < 53 * 32; i += 256) sWe[i] = We[i];
    for (int i = tid; i < 1024; i += 256) sW[i] = Wp[i];
    if (tid < 32) { sv[0][tid] = be[tid]; sv[1][tid] = a0[tid]; sv[2][tid] = a1[tid]; sbp[tid] = bp[tid]; }
    int local = tid >> 5, f = tid & 31;
    int node = blockIdx.x * 8 + local;
    if (node < n) {
        for (int k = f; k < 53; k += 32) sx[local][k] = x[(size_t)node * 53 + k];
    }
    __syncthreads();
    float xe = 0.f;
    if (node < n) {
        float acc = sv[0][f];
        for (int k = 0; k < 53; k++) acc += sx[local][k] * sWe[k * 32 + f];
        xe = fmaxf(acc, 0.f);
        xa[(size_t)node * 32 + f] = xe;
    }
    sh[local][f] = xe;
    __syncthreads();
    float accp = 0.f;
    if (node < n) {
        accp = sbp[f];
        #pragma unroll
        for (int k = 0; k < 32; k++) accp += sh[local][k] * sW[k * 32 + f];
        h[(size_t)node * 32 + f] = __float2half(accp);
    }
    __syncthreads();
    sh[local][f] = accp;
    __syncthreads();
    if (node < n && f < 8) {
        int vec = f >> 2, head = f & 3;
        const float* av = sv[1 + vec];
        float dsum = 0.f;
        #pragma unroll
        for (int dd = 0; dd < 8; dd++) dsum += sh[local][head * 8 + dd] * av[head * 8 + dd];
        (vec == 0 ? o0 : o1)[(size_t)node * 4 + head] = dsum;
    }
}

__global__ void encproj_tx_kernel(const float* __restrict__ x,
                                  const float* __restrict__ We, const float* __restrict__ be,
                                  const float* __restrict__ Wp, const float* __restrict__ bp,
                                  const float* __restrict__ a0, const float* __restrict__ a1,
                                  const float* __restrict__ a2, const float* __restrict__ a3,
                                  float* __restrict__ xt, __half* __restrict__ h,
                                  float* __restrict__ o0, float* __restrict__ o1,
                                  float* __restrict__ o2, float* __restrict__ o3, int n) {
    __shared__ float sWe[6 * 32];
    __shared__ float sW[1024];
    __shared__ float sv[5][32];
    __shared__ float sbp[32];
    __shared__ float sx[8][8];
    __shared__ float sh[8][33];
    int tid = threadIdx.x;
    for (int i = tid; i < 6 * 32; i += 256) sWe[i] = We[i];
    for (int i = tid; i < 1024; i += 256) sW[i] = Wp[i];
    if (tid < 32) {
        sv[0][tid] = be[tid]; sv[1][tid] = a0[tid]; sv[2][tid] = a1[tid];
        sv[3][tid] = a2[tid]; sv[4][tid] = a3[tid]; sbp[tid] = bp[tid];
    }
    int local = tid >> 5, f = tid & 31;
    int node = blockIdx.x * 8 + local;
    if (node < n && f < 6) sx[local][f] = x[(size_t)node * 6 + f];
    __syncthreads();
    float xe = 0.f;
    if (node < n) {
        float acc = sv[0][f];
        #pragma unroll
        for (int k = 0; k < 6; k++) acc += sx[local][k] * sWe[k * 32 + f];
        xe = fmaxf(acc, 0.f);
        xt[(size_t)node * 32 + f] = xe;
    }
    sh[local][f] = xe;
    __syncthreads();
    float accp = 0.f;
    if (node < n) {
        accp = sbp[f];
        #pragma unroll
        for (int k = 0; k < 32; k++) accp += sh[local][k] * sW[k * 32 + f];
        h[(size_t)node * 32 + f] = __float2half(accp);
    }
    __syncthreads();
    sh[local][f] = accp;
    __syncthreads();
    if (node < n && f < 16) {
        int vec = f >> 2, head = f & 3;
        const float* av = sv[1 + vec];
        float dsum = 0.f;
        #pragma unroll
        for (int dd = 0; dd < 8; dd++) dsum += sh[local][head * 8 + dd] * av[head * 8 + dd];
        float* op = vec == 0 ? o0 : vec == 1 ? o1 : vec == 2 ? o2 : o3;
        op[(size_t)node * 4 + head] = dsum;
    }
}

// ================= merged CSR aggregation (all rels) + fused semantic score =================
// 16 lanes/dst; grid-stride over rows of the concatenated dst space.
// mode 0: all rows [0,NCAT). mode 1: tx rows only (rel0+rel2; h_a may alias agg_a).
// mode 2: rel1 rows only (writes agg_a; no score).
__global__ void agg_all_kernel(
    const int* __restrict__ rowptr, const int* __restrict__ col,
    const __half* __restrict__ h_a, const __half* __restrict__ h_t,
    const float* __restrict__ asrc0, const float* __restrict__ adst0,
    const float* __restrict__ asrc1, const float* __restrict__ adst1,
    const float* __restrict__ asrc2, const float* __restrict__ adst2,
    __half* __restrict__ agg_t0, __half* __restrict__ agg_a, __half* __restrict__ agg_t2,
    const float* __restrict__ kw, const float* __restrict__ kb, const float* __restrict__ q,
    float* __restrict__ scoreOut, int NT, int NA, int mode, int nRows) {
    __shared__ float sW[1024];
    __shared__ float sb[32];
    __shared__ float sq[32];
    __shared__ float sScore[2];
    int tid = threadIdx.x;
    bool doScore = (mode != 2);
    if (doScore) {
        for (int i = tid; i < 1024; i += 256) sW[i] = kw[i];
        if (tid < 32) { sb[tid] = kb[tid]; sq[tid] = q[tid]; }
        if (tid < 2) sScore[tid] = 0.f;
        __syncthreads();
    }
    int lane = tid & 15;
    int head = lane >> 2, f0 = lane * 2;
    long stride = (long)gridDim.x * 16;
    for (long gi = (long)blockIdx.x * 16 + (tid >> 4); gi < (long)nRows; gi += stride) {
        int row;
        if (mode == 0) row = (int)gi;
        else if (mode == 1) row = (gi < NT) ? (int)gi : (int)(gi + NA);
        else row = NT + (int)gi;
        int rel, dst;
        const __half* h; const float* asrc; const float* adp; __half* agg;
        if (row < NT)           { rel = 0; dst = row;           h = h_a; asrc = asrc0; adp = adst0; agg = agg_t0; }
        else if (row < NT + NA) { rel = 1; dst = row - NT;      h = h_t; asrc = asrc1; adp = adst1; agg = agg_a; }
        else                    { rel = 2; dst = row - NT - NA; h = h_t; asrc = asrc2; adp = adst2; agg = agg_t2; }
        float ad = adp[(size_t)dst * 4 + head];
        int e0 = rowptr[row], e1 = rowptr[row + 1];
        float accx = 0.f, accy = 0.f, den = 0.f;
        for (int e = e0; e < e1; e++) {
            int s = col[e];
            float t = asrc[(size_t)s * 4 + head] + ad;
            t = t > 0.f ? t : 0.2f * t;
            float ex = __expf(t);
            den += ex;
            float2 hf = __half22float2(*(const __half2*)(h + (size_t)s * 32 + f0));
            accx += ex * hf.x; accy += ex * hf.y;
        }
        float r = 1.f / (den + 1e-16f);
        float vx = accx * r, vy = accy * r;
        __half2 o; o.x = __float2half(vx); o.y = __float2half(vy);
        *(__half2*)(agg + (size_t)dst * 32 + f0) = o;
        if (doScore && rel != 1) {
            // fused: sScore[rel] += sum_f q[f] * tanh((relu(row) @ kw + kb)[f])
            float r0 = fmaxf(vx, 0.f), r1 = fmaxf(vy, 0.f);
            float y0 = sb[f0], y1 = sb[f0 + 1];
            #pragma unroll
            for (int k = 0; k < 16; k++) {
                float rx = __shfl(r0, k, 16);
                float ry = __shfl(r1, k, 16);
                y0 += rx * sW[(2 * k) * 32 + f0]     + ry * sW[(2 * k + 1) * 32 + f0];
                y1 += rx * sW[(2 * k) * 32 + f0 + 1] + ry * sW[(2 * k + 1) * 32 + f0 + 1];
            }
            float sacc = sq[f0] * fast_tanh(y0) + sq[f0 + 1] * fast_tanh(y1);
            #pragma unroll
            for (int m = 1; m < 16; m <<= 1) sacc += __shfl_xor(sacc, m, 16);
            if (lane == 0) atomicAdd(&sScore[rel == 2 ? 1 : 0], sacc);
        }
    }
    if (doScore) {
        __syncthreads();
        if (tid < 2) unsafeAtomicAdd(scoreOut + tid, sScore[tid]);
    }
}

// ================= fused combine(layer l) + projection(layer l+1) =================
__global__ void combineproj_kernel(
    const __half* __restrict__ agg_a, const __half* __restrict__ agg_t0, const __half* __restrict__ agg_t2,
    float* __restrict__ xa, float* __restrict__ xt,
    const float* __restrict__ ln_ag, const float* __restrict__ ln_ab,
    const float* __restrict__ ln_tg, const float* __restrict__ ln_tb,
    const float* __restrict__ scores, float invNT,
    const float* __restrict__ Wa, const float* __restrict__ Ba,
    const float* __restrict__ Wt, const float* __restrict__ Bt,
    const float* __restrict__ as0, const float* __restrict__ ad1,
    const float* __restrict__ as1, const float* __restrict__ ad0,
    const float* __restrict__ as2, const float* __restrict__ ad2,
    __half* __restrict__ h_a, __half* __restrict__ h_t,
    float* __restrict__ o_as0, float* __restrict__ o_ad1,
    float* __restrict__ o_as1, float* __restrict__ o_ad0,
    float* __restrict__ o_as2, float* __restrict__ o_ad2,
    int NA_, int NT_, int nbA8, int lastProj) {
    __shared__ float sW[1024];
    __shared__ float sv[5][32];
    __shared__ float sbp[32];
    __shared__ float sh[8][33];
    int tid = threadIdx.x;
    bool isA = blockIdx.x < nbA8;
    const float* W = isA ? Wa : Wt;
    for (int i = tid; i < 1024; i += 256) sW[i] = W[i];
    if (tid < 32) {
        sbp[tid] = (isA ? Ba : Bt)[tid];
        sv[1][tid] = (isA ? as0 : as1)[tid];
        sv[2][tid] = (isA ? ad1 : ad0)[tid];
        if (!isA) { sv[3][tid] = as2[tid]; sv[4][tid] = ad2[tid]; }
    }
    int local = tid >> 5, f = tid & 31;
    int n = isA ? NA_ : NT_;
    int node = (isA ? blockIdx.x : blockIdx.x - nbA8) * 8 + local;
    float ln = 0.f;
    if (node < n) {
        float v;
        if (isA) {
            float a = __half2float(agg_a[(size_t)node * 32 + f]);
            v = fmaxf(a, 0.f) + xa[(size_t)node * 32 + f];
        } else {
            float s0 = scores[0] * invNT, s2 = scores[1] * invNT;
            float mx = fmaxf(s0, s2);
            float e0 = __expf(s0 - mx), e2 = __expf(s2 - mx);
            float inv_s = 1.f / (e0 + e2);
            float w0 = e0 * inv_s, w2 = e2 * inv_s;
            float a0 = fmaxf(__half2float(agg_t0[(size_t)node * 32 + f]), 0.f);
            float a2 = fmaxf(__half2float(agg_t2[(size_t)node * 32 + f]), 0.f);
            v = fmaxf(w0 * a0 + w2 * a2, 0.f) + xt[(size_t)node * 32 + f];
        }
        float m = v;
        #pragma unroll
        for (int mask = 1; mask < 32; mask <<= 1) m += __shfl_xor(m, mask, 64);
        m *= (1.f / 32.f);
        float d = v - m;
        float var = d * d;
        #pragma unroll
        for (int mask = 1; mask < 32; mask <<= 1) var += __shfl_xor(var, mask, 64);
        var *= (1.f / 32.f);
        float inv = 1.f / sqrtf(var + 1e-5f);
        ln = d * inv * (isA ? ln_ag : ln_tg)[f] + (isA ? ln_ab : ln_tb)[f];
        if (isA || !lastProj) (isA ? xa : xt)[(size_t)node * 32 + f] = ln;
    }
    sh[local][f] = ln;
    __syncthreads();
    float accp = 0.f;
    if (node < n) {
        accp = sbp[f];
        #pragma unroll
        for (int k = 0; k < 32; k++) accp += sh[local][k] * sW[k * 32 + f];
        if (!isA || !lastProj) (isA ? h_a : h_t)[(size_t)node * 32 + f] = __float2half(accp);
    }
    __syncthreads();
    sh[local][f] = accp;
    __syncthreads();
    int nvec = isA ? 8 : 16;
    if (node < n && f < nvec) {
        int vec = f >> 2, head = f & 3;
        // layer-3 consumers: only rel1 (src=tx: as1; dst=addr: ad1)
        bool need = !lastProj || (isA ? (vec == 1) : (vec == 0));
        if (need) {
            const float* av = sv[1 + vec];
            float dsum = 0.f;
            #pragma unroll
            for (int dd = 0; dd < 8; dd++) dsum += sh[local][head * 8 + dd] * av[head * 8 + dd];
            float* op;
            if (isA) op = vec == 0 ? o_as0 : o_ad1;
            else op = vec == 0 ? o_as1 : vec == 1 ? o_ad0 : vec == 2 ? o_as2 : o_ad2;
            op[(size_t)node * 4 + head] = dsum;
        }
    }
}

// ================= layer-3 combine_addr + output head =================
__global__ void combine_final_kernel(const __half* __restrict__ agg_a, const float* __restrict__ xa,
                                     const float* __restrict__ g, const float* __restrict__ bt,
                                     const float* __restrict__ lw, const float* __restrict__ lb,
                                     float* __restrict__ out, int n) {
    int tid = threadIdx.x;
    int local = tid >> 5, f = tid & 31;
    int node = blockIdx.x * 8 + local;
    if (node >= n) return;
    float a = __half2float(agg_a[(size_t)node * 32 + f]);
    float v = fmaxf(a, 0.f) + xa[(size_t)node * 32 + f];
    float m = v;
    #pragma unroll
    for (int mask = 1; mask < 32; mask <<= 1) m += __shfl_xor(m, mask, 64);
    m *= (1.f / 32.f);
    float d = v - m;
    float var = d * d;
    #pragma unroll
    for (int mask = 1; mask < 32; mask <<= 1) var += __shfl_xor(var, mask, 64);
    var *= (1.f / 32.f);
    float inv = 1.f / sqrtf(var + 1e-5f);
    float ln = d * inv * g[f] + bt[f];
    float p0 = ln * lw[f * 2 + 0];
    float p1 = ln * lw[f * 2 + 1];
    #pragma unroll
    for (int mask = 1; mask < 32; mask <<= 1) {
        p0 += __shfl_xor(p0, mask, 64);
        p1 += __shfl_xor(p1, mask, 64);
    }
    if (f == 0) {
        out[(size_t)node * 2 + 0] = p0 + lb[0];
        out[(size_t)node * 2 + 1] = p1 + lb[1];
    }
}

extern "C" void kernel_launch(void* const* d_in, const int* in_sizes, int n_in,
                              void* d_out, int out_size, void* d_ws, size_t ws_size,
                              hipStream_t stream) {
    const float* x_addr = (const float*)d_in[0];
    const float* x_tx   = (const float*)d_in[1];
    const int* ei_in    = (const int*)d_in[2];
    const int* ei_out   = (const int*)d_in[3];
    const int* ei_sp    = (const int*)d_in[4];
    const float* enc_w_addr = (const float*)d_in[5];
    const float* enc_b_addr = (const float*)d_in[6];
    const float* enc_w_tx   = (const float*)d_in[7];
    const float* enc_b_tx   = (const float*)d_in[8];
    const float* ln_ag = (const float*)d_in[9];
    const float* ln_ab = (const float*)d_in[10];
    const float* ln_tg = (const float*)d_in[11];
    const float* ln_tb = (const float*)d_in[12];
    const float* pw_a = (const float*)d_in[13];
    const float* pb_a = (const float*)d_in[14];
    const float* pw_t = (const float*)d_in[15];
    const float* pb_t = (const float*)d_in[16];
    const float* att_src = (const float*)d_in[17];
    const float* att_dst = (const float*)d_in[18];
    const float* klw = (const float*)d_in[19];
    const float* klb = (const float*)d_in[20];
    const float* qv  = (const float*)d_in[21];
    const float* lin_w = (const float*)d_in[22];
    const float* lin_b = (const float*)d_in[23];
    float* out = (float*)d_out;

    const int NA = in_sizes[0] / 53;
    const int NT = in_sizes[1] / 6;
    const int E_IN = in_sizes[2] / 2;
    const int E_OUT = in_sizes[3] / 2;
    const int E_SP = in_sizes[4] / 2;
    const int E_TOT = E_IN + E_OUT + E_SP;
    const int NCAT = NT + NA + NT;

    size_t off = 0;
    float* base = (float*)d_ws;
    auto alloc = [&](size_t nfloats) {
        float* p = base + off;
        off += (nfloats + 63) & ~(size_t)63;
        return p;
    };
    float* xa      = alloc((size_t)NA * 32);
    float* xt      = alloc((size_t)NT * 32);
    float* agg_a_f = alloc((size_t)NA * 16);
    float* agg_t0f = alloc((size_t)NT * 16);
    float* agg_t2f = alloc((size_t)NT * 16);
    float* h_t_f   = alloc((size_t)NT * 16);
    float* asrc0a  = alloc((size_t)NA * 4);
    float* adst1a  = alloc((size_t)NA * 4);
    float* asrc1t  = alloc((size_t)NT * 4);
    float* adst0t  = alloc((size_t)NT * 4);
    float* asrc2t  = alloc((size_t)NT * 4);
    float* adst2t  = alloc((size_t)NT * 4);
    int* rowptrAll = (int*)alloc((size_t)NCAT + 64);
    int* colAll    = (int*)alloc((size_t)E_TOT);
    size_t tmp_span = (((size_t)NCAT + 63) & ~(size_t)63) + 1088 + 64;
    int* tmp       = (int*)alloc((size_t)NCAT);
    int* bsum      = (int*)alloc(1088);
    float* scores  = alloc(64);

    // optionally un-alias h_a from agg_a if workspace is big enough
    size_t ha_floats = (((size_t)NA * 16) + 63) & ~(size_t)63;
    bool roomy = ((off + ha_floats) * sizeof(float)) <= ws_size;
    float* h_a_f = roomy ? alloc((size_t)NA * 16) : agg_a_f;

    __half* agg_a  = (__half*)agg_a_f;
    __half* agg_t0 = (__half*)agg_t0f;
    __half* agg_t2 = (__half*)agg_t2f;
    __half* h_t    = (__half*)h_t_f;
    __half* h_a    = (__half*)h_a_f;

    dim3 blk(256);
    int nbA8 = (NA + 7) / 8, nbT8 = (NT + 7) / 8;
    int nbE = (E_TOT + 255) / 256;
    int nbScan = (NCAT + 1023) / 1024;

    // ---- CSR build (once) + zero deg/bsum/scores ----
    zero_int_kernel<<<2048, blk, 0, stream>>>(tmp, (long)tmp_span);
    hist_kernel<<<nbE, blk, 0, stream>>>(ei_in, ei_out, ei_sp, E_IN, E_OUT, E_SP, NT, NA, tmp);
    scan1_kernel<<<nbScan, blk, 0, stream>>>(tmp, rowptrAll, bsum, NCAT);
    scan2_kernel<<<1, 1024, 0, stream>>>(bsum, nbScan);
    scan3_kernel<<<(NCAT + 255) / 256, blk, 0, stream>>>(rowptrAll, bsum, tmp, NCAT, E_TOT);
    scatter_kernel<<<nbE, blk, 0, stream>>>(ei_in, ei_out, ei_sp, E_IN, E_OUT, E_SP, NT, NA, tmp, colAll);

    // ---- fused encoder + layer-0 projection ----
    encproj_addr_kernel<<<nbA8, blk, 0, stream>>>(
        x_addr, enc_w_addr, enc_b_addr, pw_a, pb_a,
        att_src + 0 * 32, att_dst + 1 * 32,
        xa, h_a, asrc0a, adst1a, NA);
    encproj_tx_kernel<<<nbT8, blk, 0, stream>>>(
        x_tx, enc_w_tx, enc_b_tx, pw_t, pb_t,
        att_src + 1 * 32, att_dst + 0 * 32, att_src + 2 * 32, att_dst + 2 * 32,
        xt, h_t, asrc1t, adst0t, asrc2t, adst2t, NT);

    auto agg_launch = [&](int mode, int nRows, const float* kw, const float* kb,
                          const float* q, float* sc) {
        int blocks = (nRows + 15) / 16;
        if (blocks > 2048) blocks = 2048;
        agg_all_kernel<<<blocks, blk, 0, stream>>>(
            rowptrAll, colAll, h_a, h_t,
            asrc0a, adst0t, asrc1t, adst1a, asrc2t, adst2t,
            agg_t0, agg_a, agg_t2, kw, kb, q, sc, NT, NA, mode, nRows);
    };

    for (int l = 0; l < NLAYERS; l++) {
        bool last = (l == NLAYERS - 1);
        const float* kw = klw + l * 1024;
        const float* kb = klb + l * 32;
        const float* q  = qv + l * 32;
        float* sc = scores + 2 * l;
        if (!last) {
            if (roomy) {
                agg_launch(0, NCAT, kw, kb, q, sc);
            } else {
                agg_launch(1, 2 * NT, kw, kb, q, sc);  // rel0+rel2 (h_a alias still live)
                agg_launch(2, NA, kw, kb, q, sc);      // rel1 (overwrites h_a region)
            }
            int lp = l + 1;
            combineproj_kernel<<<nbA8 + nbT8, blk, 0, stream>>>(
                agg_a, agg_t0, agg_t2, xa, xt,
                ln_ag, ln_ab, ln_tg, ln_tb,
                sc, 1.0f / (float)NT,
                pw_a + lp * 1024, pb_a + lp * 32, pw_t + lp * 1024, pb_t + lp * 32,
                att_src + (lp * 3 + 0) * 32, att_dst + (lp * 3 + 1) * 32,
                att_src + (lp * 3 + 1) * 32, att_dst + (lp * 3 + 0) * 32,
                att_src + (lp * 3 + 2) * 32, att_dst + (lp * 3 + 2) * 32,
                h_a, h_t,
                asrc0a, adst1a, asrc1t, adst0t, asrc2t, adst2t,
                NA, NT, nbA8, lp == 3 ? 1 : 0);
        } else {
            agg_launch(2, NA, kw, kb, q, sc);          // rel1 only
            combine_final_kernel<<<nbA8, blk, 0, stream>>>(agg_a, xa, ln_ag, ln_ab,
                                                           lin_w, lin_b, out, NA);
        }
    }
}